// Round 19
// baseline (1295.745 us; speedup 1.0000x reference)
//
#include <hip/hip_runtime.h>

#define B_   4
#define TT_  2048
#define C_   2048
#define H_   32
#define S_   64
#define DF_  7168
#define TCH  512
#define NCH  4

typedef unsigned short u16;
typedef __bf16 bf16x8 __attribute__((ext_vector_type(8)));
typedef float  f32x4  __attribute__((ext_vector_type(4)));

__device__ __forceinline__ u16 f2bf(float f) {
  unsigned u = __builtin_bit_cast(unsigned, f);
  u = u + 0x7FFFu + ((u >> 16) & 1u);
  return (u16)(u >> 16);
}
__device__ __forceinline__ float bf2f(u16 v) {
  unsigned u = ((unsigned)v) << 16;
  return __builtin_bit_cast(float, u);
}

#define GLOAD16(g, l) __builtin_amdgcn_global_load_lds( \
    (const __attribute__((address_space(1))) void*)(g), \
    (__attribute__((address_space(3))) void*)(l), 16, 0, 0)

__device__ __forceinline__ void vmcnt6() { asm volatile("s_waitcnt vmcnt(6)" ::: "memory"); }
__device__ __forceinline__ void vmcnt0() { asm volatile("s_waitcnt vmcnt(0)" ::: "memory"); }

// ---- weight convert+transpose ----------------------------------------------
__global__ __launch_bounds__(256) void wcvt_t(const float* __restrict__ W,
                                              u16* __restrict__ Wt, int K, int Nfull,
                                              int n0off) {
  __shared__ alignas(16) float tile[32][33];
  int nloc = blockIdx.x * 32, k0 = blockIdx.y * 32;
  int tx = threadIdx.x & 31, ty = threadIdx.x >> 5;
  for (int r = ty; r < 32; r += 8)
    tile[r][tx] = W[(size_t)(k0 + r) * Nfull + n0off + nloc + tx];
  __syncthreads();
  for (int r = ty; r < 32; r += 8)
    Wt[(size_t)(nloc + r) * K + k0 + tx] = f2bf(tile[tx][r]);
}

// ---- layernorm over C=2048, f32 in -> bf16 out ------------------------------
__global__ __launch_bounds__(256) void ln_rows(const float* __restrict__ x,
                                               const float* __restrict__ g,
                                               const float* __restrict__ b,
                                               u16* __restrict__ out) {
  const int row = blockIdx.x;
  const float* xr = x + (size_t)row * C_;
  float v[8]; float s = 0.f, s2 = 0.f;
#pragma unroll
  for (int i = 0; i < 8; i++) { v[i] = xr[threadIdx.x + i * 256]; s += v[i]; s2 += v[i] * v[i]; }
#pragma unroll
  for (int o = 32; o > 0; o >>= 1) { s += __shfl_down(s, o); s2 += __shfl_down(s2, o); }
  __shared__ float rs[4], rs2[4];
  int wid = threadIdx.x >> 6, lane = threadIdx.x & 63;
  if (lane == 0) { rs[wid] = s; rs2[wid] = s2; }
  __syncthreads();
  s = rs[0] + rs[1] + rs[2] + rs[3];
  s2 = rs2[0] + rs2[1] + rs2[2] + rs2[3];
  float m = s * (1.f / C_);
  float var = s2 * (1.f / C_) - m * m;
  float inv = rsqrtf(var + 1e-5f);
  u16* orow = out + (size_t)row * C_;
#pragma unroll
  for (int i = 0; i < 8; i++) {
    int c = threadIdx.x + i * 256;
    orow[c] = f2bf((v[i] - m) * inv * g[c] + b[c]);
  }
}

// ---- decay tables -----------------------------------------------------------
__global__ void wtabs_k(const float* __restrict__ td, float* __restrict__ wb_tab,
                        float* __restrict__ wk_tab, float* __restrict__ wspow) {
  int h = blockIdx.x, t = threadIdx.x;
  float w = expf(-expf(td[h]));
  wb_tab[h * TCH + t] = powf(w, (float)t);
  wk_tab[h * TCH + t] = powf(w, (float)(TCH - 1 - t));
  if (t == 0) wspow[h] = powf(w, (float)TCH);
}

// ---- time-shift mixes -------------------------------------------------------
__device__ __forceinline__ void mix_body(const u16* cur, const u16* prev, bool hasp,
                                         const float* mc, u16* dst) {
  ushort4 c0 = *(const ushort4*)cur;
  ushort4 c1 = *(const ushort4*)(cur + 4);
  ushort4 p0 = {0, 0, 0, 0}, p1 = {0, 0, 0, 0};
  if (hasp) { p0 = *(const ushort4*)prev; p1 = *(const ushort4*)(prev + 4); }
  float4 mA = *(const float4*)mc;
  float4 mB = *(const float4*)(mc + 4);
  ushort4 r0, r1;
  r0.x = f2bf(bf2f(c0.x) * mA.x + bf2f(p0.x) * (1.f - mA.x));
  r0.y = f2bf(bf2f(c0.y) * mA.y + bf2f(p0.y) * (1.f - mA.y));
  r0.z = f2bf(bf2f(c0.z) * mA.z + bf2f(p0.z) * (1.f - mA.z));
  r0.w = f2bf(bf2f(c0.w) * mA.w + bf2f(p0.w) * (1.f - mA.w));
  r1.x = f2bf(bf2f(c1.x) * mB.x + bf2f(p1.x) * (1.f - mB.x));
  r1.y = f2bf(bf2f(c1.y) * mB.y + bf2f(p1.y) * (1.f - mB.y));
  r1.z = f2bf(bf2f(c1.z) * mB.z + bf2f(p1.z) * (1.f - mB.z));
  r1.w = f2bf(bf2f(c1.w) * mB.w + bf2f(p1.w) * (1.f - mB.w));
  *(ushort4*)dst = r0;
  *(ushort4*)(dst + 4) = r1;
}

__global__ __launch_bounds__(256) void mix3(const u16* __restrict__ h,
                                            const float* __restrict__ mk,
                                            const float* __restrict__ mv,
                                            const float* __restrict__ mr,
                                            u16* __restrict__ xk, u16* __restrict__ xv,
                                            u16* __restrict__ xr) {
  size_t i8 = (size_t)blockIdx.x * 256 + threadIdx.x;
  size_t off = i8 * 8;
  int c0 = (int)(off & (C_ - 1));
  int row = (int)(i8 >> 8);
  bool hasp = (row & (TT_ - 1)) != 0;
  const u16* cur = h + off;
  const u16* prev = cur - C_;
  mix_body(cur, prev, hasp, mk + c0, xk + off);
  mix_body(cur, prev, hasp, mv + c0, xv + off);
  mix_body(cur, prev, hasp, mr + c0, xr + off);
}

__global__ __launch_bounds__(256) void mix2(const u16* __restrict__ h,
                                            const float* __restrict__ mk,
                                            const float* __restrict__ mr,
                                            u16* __restrict__ xk, u16* __restrict__ xr) {
  size_t i8 = (size_t)blockIdx.x * 256 + threadIdx.x;
  size_t off = i8 * 8;
  int c0 = (int)(off & (C_ - 1));
  int row = (int)(i8 >> 8);
  bool hasp = (row & (TT_ - 1)) != 0;
  const u16* cur = h + off;
  const u16* prev = cur - C_;
  mix_body(cur, prev, hasp, mk + c0, xk + off);
  mix_body(cur, prev, hasp, mr + c0, xr + off);
}

// ---- gemm5 (unified): BM=128, BN=256, BK=64, 512 thr / 8 waves (2M x 4N),
// wave tile 64x64 (acc[4][4]). 3-buffer ring (144 KB LDS), depth-2 prefetch:
// tile t stages ALL 6 loads of tile t+2 in phase 1 (into buf holding t-1's
// dead data); single counted vmcnt(6) at p2-end drains t+1's 6 loads (issued
// a full tile earlier), leaving t+2's in flight; ONE barrier per tile
// (cross-wave landing of t+1 data + WAR on the ring). Validated r12/r17/r18.
// EPI: 0 = bf16 store ; 1 = f32 out = acc + res ; 2 = bf16 relu(acc)^2 ;
//      3 = bf16 sigmoid ; 9 = f32 out = out + bf16(sr)*acc
template <int EPI>
__global__ __launch_bounds__(512) void gemm5(const u16* __restrict__ A,
                                             const u16* __restrict__ Bt,
                                             void* __restrict__ Cv,
                                             const float* __restrict__ res,
                                             const u16* __restrict__ srp,
                                             int N, int K, int lda, int ldb, int gy) {
  __shared__ alignas(16) char smem[3 * 49152];
  const int nwg = gridDim.x, qq = nwg >> 3;
  const int wg = (int)(blockIdx.x & 7) * qq + (int)(blockIdx.x >> 3);
  const int bx = wg / gy, by = wg % gy;
  const int tid = threadIdx.x, w = tid >> 6, lane = tid & 63;
  const int fr = lane & 15, fq = lane >> 4;
  const int m0 = bx * 128, n0 = by * 256;
  const int wm = (w >> 2) * 64, wn = (w & 3) * 64;
  const int rowS = tid >> 3;
  const int colS = ((tid & 7) * 8) ^ ((rowS & 7) << 3);  // T2 inverse-swizzled source
  const u16* Ag = A + (size_t)(m0 + rowS) * lda + colS;
  const u16* Bg = Bt + (size_t)(n0 + rowS) * ldb + colS;
  const int NT = K >> 6;

  f32x4 acc[4][4];
#pragma unroll
  for (int m = 0; m < 4; m++)
#pragma unroll
    for (int n = 0; n < 4; n++) acc[m][n] = (f32x4){0.f, 0.f, 0.f, 0.f};

#define STG_A(buf, k0, j) GLOAD16(Ag + (size_t)((j) * 64) * lda + (k0), \
    smem + (buf) * 49152 + (j) * 8192 + w * 1024)
#define STG_B(buf, k0, j) GLOAD16(Bg + (size_t)((j) * 64) * ldb + (k0), \
    smem + (buf) * 49152 + 16384 + (j) * 8192 + w * 1024)
#define RD_A(buf, kk, m) (*(const bf16x8*)(smem + (buf) * 49152 + \
    ((((wm + (m) * 16 + fr) * 128) + (kk) * 64 + fq * 16) ^ (((wm + (m) * 16 + fr) & 7) << 4))))
#define RD_B(buf, kk, n) (*(const bf16x8*)(smem + (buf) * 49152 + 16384 + \
    ((((wn + (n) * 16 + fr) * 128) + (kk) * 64 + fq * 16) ^ (((wn + (n) * 16 + fr) & 7) << 4))))

  // prologue: stage tiles 0 and 1 (6 loads each); wait tile 0 only
  STG_A(0, 0, 0); STG_A(0, 0, 1);
  STG_B(0, 0, 0); STG_B(0, 0, 1); STG_B(0, 0, 2); STG_B(0, 0, 3);
  STG_A(1, 64, 0); STG_A(1, 64, 1);
  STG_B(1, 64, 0); STG_B(1, 64, 1); STG_B(1, 64, 2); STG_B(1, 64, 3);
  vmcnt6();
  __builtin_amdgcn_s_barrier();

  int bufc = 0;
  for (int t = 0; t < NT; t++) {
    int b2 = bufc + 2; if (b2 >= 3) b2 -= 3;
    const bool st = (t + 2) < NT;
    const int k2 = (t + 2) << 6;
    bf16x8 av[4], bv[4];

    // ---- phase 1: kk0, 16 MFMA; stage ALL of tile t+2 (max flight time) ----
#pragma unroll
    for (int m = 0; m < 4; m++) av[m] = RD_A(bufc, 0, m);
#pragma unroll
    for (int n = 0; n < 4; n++) bv[n] = RD_B(bufc, 0, n);
    if (st) {
      STG_A(b2, k2, 0); STG_A(b2, k2, 1);
      STG_B(b2, k2, 0); STG_B(b2, k2, 1); STG_B(b2, k2, 2); STG_B(b2, k2, 3);
    }
    __builtin_amdgcn_s_setprio(1);
#pragma unroll
    for (int m = 0; m < 4; m++)
#pragma unroll
      for (int n = 0; n < 4; n++)
        acc[m][n] = __builtin_amdgcn_mfma_f32_16x16x32_bf16(av[m], bv[n], acc[m][n], 0, 0, 0);
    __builtin_amdgcn_s_setprio(0);

    // ---- phase 2: kk1, 16 MFMA ----
#pragma unroll
    for (int m = 0; m < 4; m++) av[m] = RD_A(bufc, 1, m);
#pragma unroll
    for (int n = 0; n < 4; n++) bv[n] = RD_B(bufc, 1, n);
    if (st) vmcnt6(); else vmcnt0();  // drain tile t+1's 6 loads; keep t+2's
    __builtin_amdgcn_s_setprio(1);
#pragma unroll
    for (int m = 0; m < 4; m++)
#pragma unroll
      for (int n = 0; n < 4; n++)
        acc[m][n] = __builtin_amdgcn_mfma_f32_16x16x32_bf16(av[m], bv[n], acc[m][n], 0, 0, 0);
    __builtin_amdgcn_s_setprio(0);
    __builtin_amdgcn_s_barrier();     // single per-tile barrier

    bufc = bufc + 1 == 3 ? 0 : bufc + 1;
  }
#undef STG_A
#undef STG_B
#undef RD_A
#undef RD_B

#pragma unroll
  for (int m = 0; m < 4; m++)
#pragma unroll
    for (int n = 0; n < 4; n++)
#pragma unroll
      for (int j = 0; j < 4; j++) {
        int row = m0 + wm + m * 16 + fq * 4 + j;
        int col = n0 + wn + n * 16 + fr;
        size_t idx = (size_t)row * N + col;
        float v = acc[m][n][j];
        if (EPI == 0) ((u16*)Cv)[idx] = f2bf(v);
        else if (EPI == 1) ((float*)Cv)[idx] = v + res[idx];
        else if (EPI == 2) { float r = v > 0.f ? v : 0.f; ((u16*)Cv)[idx] = f2bf(r * r); }
        else if (EPI == 3) ((u16*)Cv)[idx] = f2bf(1.f / (1.f + expf(-v)));
        else {
          float pvv = ((float*)Cv)[idx];
          ((float*)Cv)[idx] = pvv + bf2f(srp[idx]) * v;
        }
      }
}

// ---- kvsum: per-chunk S_c[s][sv] = sum_t wk[t]*K[t][s]*V[t][sv]  (MFMA) -----
__global__ __launch_bounds__(256) void kvsum_m(const u16* __restrict__ K,
                                               const u16* __restrict__ V,
                                               const float* __restrict__ wk_tab,
                                               float* __restrict__ SC) {
  const int bh = blockIdx.x & 127, c = blockIdx.x >> 7;
  const int b = bh >> 5, h = bh & 31;
  const int tid = threadIdx.x, w = tid >> 6, lane = tid & 63;
  const int fr = lane & 15, fq = lane >> 4;
  const size_t chunkbase = (size_t)b * TT_ + (size_t)c * TCH;
  const u16* Kp = K + chunkbase * C_ + h * 64;
  const u16* Vp = V + chunkbase * C_ + h * 64;
  __shared__ alignas(16) u16 Kts[64 * 128];
  __shared__ alignas(16) u16 Vts[64 * 128];
  f32x4 acc[4];
#pragma unroll
  for (int n = 0; n < 4; n++) acc[n] = (f32x4){0.f, 0.f, 0.f, 0.f};

  for (int tb = 0; tb < 4; tb++) {
    __syncthreads();
    const int u = tid >> 1;
    const int tg = tb * 128 + u;
    const float wkv = wk_tab[h * TCH + tg];
#pragma unroll
    for (int i = 0; i < 4; i++) {
      int s0 = (tid & 1) * 32 + i * 8;
      uint4 dK = *(const uint4*)(Kp + (size_t)tg * C_ + s0);
      uint4 dV = *(const uint4*)(Vp + (size_t)tg * C_ + s0);
      const u16* ek = (const u16*)&dK;
      const u16* ev = (const u16*)&dV;
#pragma unroll
      for (int j = 0; j < 8; j++) {
        int s = s0 + j;
        int byte = s * 256 + u * 2;
        byte ^= (s & 7) << 4;
        *(u16*)((char*)Kts + byte) = f2bf(bf2f(ek[j]) * wkv);
        *(u16*)((char*)Vts + byte) = ev[j];
      }
    }
    __syncthreads();
#pragma unroll
    for (int kk = 0; kk < 4; kk++) {
      int rbyteA = (w * 16 + fr) * 256 + kk * 64 + fq * 16;
      rbyteA ^= (fr & 7) << 4;
      bf16x8 av = *(const bf16x8*)((char*)Kts + rbyteA);
#pragma unroll
      for (int n = 0; n < 4; n++) {
        int rbyteB = (n * 16 + fr) * 256 + kk * 64 + fq * 16;
        rbyteB ^= (fr & 7) << 4;
        bf16x8 bv = *(const bf16x8*)((char*)Vts + rbyteB);
        acc[n] = __builtin_amdgcn_mfma_f32_16x16x32_bf16(av, bv, acc[n], 0, 0, 0);
      }
    }
  }
  float* out = SC + ((size_t)c * 128 + bh) * 4096;
#pragma unroll
  for (int n = 0; n < 4; n++)
#pragma unroll
    for (int j = 0; j < 4; j++) {
      int srow = w * 16 + fq * 4 + j;
      int scol = n * 16 + fr;
      out[srow * 64 + scol] = acc[n][j];
    }
}

// ---- state combine: STt[c][s][sp] = bf16( sum_{j<c} ws^(c-1-j) SC[j][sp][s] )
__global__ __launch_bounds__(256) void stcomb(const float* __restrict__ SC,
                                              u16* __restrict__ STt,
                                              const float* __restrict__ wspow) {
  const int bh = blockIdx.x;
  const float ws = wspow[bh & 31];
  const int tid = threadIdx.x;
#pragma unroll
  for (int e = 0; e < 16; e++) {
    int idxT = e * 256 + tid;
    int s = idxT >> 6, sp = idxT & 63;
    int src = sp * 64 + s;
    float st = 0.f;
#pragma unroll
    for (int c = 0; c < 4; c++) {
      STt[((size_t)c * 128 + bh) * 4096 + idxT] = f2bf(st);
      st = ws * st + SC[((size_t)c * 128 + bh) * 4096 + src];
    }
  }
}

// ---- attention output (MFMA, batched over chunks; 34KB LDS) -----------------
__global__ __launch_bounds__(256) void att_out_m(const u16* __restrict__ R,
                                                 const u16* __restrict__ K,
                                                 const u16* __restrict__ V,
                                                 const u16* __restrict__ STt,
                                                 const float* __restrict__ wb_tab,
                                                 const float* __restrict__ u_vec,
                                                 u16* __restrict__ xa) {
  const int bh = blockIdx.x;
  const int ti = blockIdx.y;
  const int c  = blockIdx.z;
  const int b = bh >> 5, h = bh & 31;
  const int tid = threadIdx.x, w = tid >> 6, lane = tid & 63;
  const int fr = lane & 15, fq = lane >> 4;
  const int t0 = ti * 64;
  const size_t chunkbase = (size_t)b * TT_ + (size_t)c * TCH;
  const u16* Rp = R + (chunkbase + t0) * C_ + h * 64;
  const u16* Kp = K + chunkbase * C_ + h * 64;
  const u16* Vp = V + chunkbase * C_ + h * 64;

  __shared__ alignas(16) u16 Rs[64 * 64];
  __shared__ alignas(16) u16 Ks[64 * 64];
  __shared__ alignas(16) u16 Vts[64 * 64];
  __shared__ alignas(16) u16 Xs[64 * 64];
  __shared__ float wbs[512];

#pragma unroll
  for (int it = 0; it < 2; it++) {
    int r = (tid >> 3) + it * 32;
    int cb = (tid & 7) * 16;
    uint4 d = *(const uint4*)((const char*)(Rp + (size_t)r * C_) + cb);
    int byte = (r * 128 + cb) ^ ((r & 7) << 4);
    *(uint4*)((char*)Rs + byte) = d;
  }
  const u16* stg = STt + ((size_t)c * 128 + bh) * 4096;
#pragma unroll
  for (int it = 0; it < 2; it++) {
    int s = (tid >> 3) + it * 32;
    int cb = (tid & 7) * 16;
    uint4 d = *(const uint4*)((const char*)(stg + (size_t)s * 64) + cb);
    int byte = (s * 128 + cb) ^ ((s & 7) << 4);
    *(uint4*)((char*)Xs + byte) = d;
  }
  wbs[tid] = wb_tab[h * TCH + tid];
  wbs[tid + 256] = wb_tab[h * TCH + tid + 256];
  const float uh = u_vec[h];
  __syncthreads();

  f32x4 pv[4];
#pragma unroll
  for (int n = 0; n < 4; n++) pv[n] = (f32x4){0.f, 0.f, 0.f, 0.f};
#pragma unroll
  for (int kk = 0; kk < 2; kk++) {
    int rbA = ((w * 16 + fr) * 128 + kk * 64 + fq * 16) ^ ((fr & 7) << 4);
    bf16x8 av = *(const bf16x8*)((char*)Rs + rbA);
#pragma unroll
    for (int n = 0; n < 4; n++) {
      int rbB = ((n * 16 + fr) * 128 + kk * 64 + fq * 16) ^ ((fr & 7) << 4);
      bf16x8 bv = *(const bf16x8*)((char*)Xs + rbB);
      pv[n] = __builtin_amdgcn_mfma_f32_16x16x32_bf16(av, bv, pv[n], 0, 0, 0);
    }
  }
#pragma unroll
  for (int n = 0; n < 4; n++)
#pragma unroll
    for (int j = 0; j < 4; j++) {
      int tg = t0 + w * 16 + fq * 4 + j;
      pv[n][j] *= wbs[tg];
    }

  for (int ub = 0; ub <= ti; ub++) {
    const int u0 = ub * 64;
    __syncthreads();
#pragma unroll
    for (int it = 0; it < 2; it++) {
      int r = (tid >> 3) + it * 32;
      int cb = (tid & 7) * 16;
      uint4 d = *(const uint4*)((const char*)(Kp + (size_t)(u0 + r) * C_) + cb);
      int byte = (r * 128 + cb) ^ ((r & 7) << 4);
      *(uint4*)((char*)Ks + byte) = d;
    }
#pragma unroll
    for (int it = 0; it < 2; it++) {
      int u = (tid >> 3) + it * 32;
      int s0 = (tid & 7) * 8;
      uint4 d = *(const uint4*)(Vp + (size_t)(u0 + u) * C_ + s0);
      const u16* ev = (const u16*)&d;
#pragma unroll
      for (int j = 0; j < 8; j++) {
        int s = s0 + j;
        int byte = (s * 128 + u * 2) ^ ((s & 7) << 4);
        *(u16*)((char*)Vts + byte) = ev[j];
      }
    }
    __syncthreads();
    f32x4 accA[4];
#pragma unroll
    for (int n = 0; n < 4; n++) accA[n] = (f32x4){0.f, 0.f, 0.f, 0.f};
#pragma unroll
    for (int kk = 0; kk < 2; kk++) {
      int rbA = ((w * 16 + fr) * 128 + kk * 64 + fq * 16) ^ ((fr & 7) << 4);
      bf16x8 av = *(const bf16x8*)((char*)Rs + rbA);
#pragma unroll
      for (int n = 0; n < 4; n++) {
        int rbB = ((n * 16 + fr) * 128 + kk * 64 + fq * 16) ^ ((fr & 7) << 4);
        bf16x8 bv = *(const bf16x8*)((char*)Ks + rbB);
        accA[n] = __builtin_amdgcn_mfma_f32_16x16x32_bf16(av, bv, accA[n], 0, 0, 0);
      }
    }
#pragma unroll
    for (int n = 0; n < 4; n++) {
#pragma unroll
      for (int j = 0; j < 4; j++) {
        int tl = w * 16 + fq * 4 + j;
        int tg = t0 + tl;
        int u = u0 + n * 16 + fr;
        int d = tg - u;
        float f = (d > 0) ? wbs[d - 1] : ((d == 0) ? uh : 0.f);
        int byte = (tl * 128 + (n * 16 + fr) * 2) ^ ((tl & 7) << 4);
        *(u16*)((char*)Xs + byte) = f2bf(accA[n][j] * f);
      }
    }
#pragma unroll
    for (int kk = 0; kk < 2; kk++) {
      int rbA = ((w * 16 + fr) * 128 + kk * 64 + fq * 16) ^ ((fr & 7) << 4);
      bf16x8 ap = *(const bf16x8*)((char*)Xs + rbA);
#pragma unroll
      for (int n = 0; n < 4; n++) {
        int rbB = ((n * 16 + fr) * 128 + kk * 64 + fq * 16) ^ ((fr & 7) << 4);
        bf16x8 vp = *(const bf16x8*)((char*)Vts + rbB);
        pv[n] = __builtin_amdgcn_mfma_f32_16x16x32_bf16(ap, vp, pv[n], 0, 0, 0);
      }
    }
  }
  u16* xout = xa + (chunkbase + t0) * C_ + h * 64;
#pragma unroll
  for (int n = 0; n < 4; n++)
#pragma unroll
    for (int j = 0; j < 4; j++) {
      int tl = w * 16 + fq * 4 + j;
      xout[(size_t)tl * C_ + n * 16 + fr] = f2bf(pv[n][j]);
    }
}

// ---- per-head groupnorm ------------------------------------------------------
__global__ __launch_bounds__(256) void gnorm(const u16* __restrict__ xa,
                                             const float* __restrict__ g,
                                             const float* __restrict__ b,
                                             u16* __restrict__ out) {
  const int row = blockIdx.x;
  const int lane = threadIdx.x & 63, wv = threadIdx.x >> 6;
  const u16* xp = xa + (size_t)row * C_;
  u16* op = out + (size_t)row * C_;
  for (int h = wv; h < 32; h += 4) {
    float v = bf2f(xp[h * 64 + lane]) * 0.125f;
    float s = v, s2 = v * v;
#pragma unroll
    for (int o = 32; o > 0; o >>= 1) { s += __shfl_down(s, o); s2 += __shfl_down(s2, o); }
    s = __shfl(s, 0); s2 = __shfl(s2, 0);
    float m = s * (1.f / 64.f), var = s2 * (1.f / 64.f) - m * m;
    float nv = (v - m) * rsqrtf(var + 1e-5f);
    op[h * 64 + lane] = f2bf(nv * g[h * 64 + lane] + b[h * 64 + lane]);
  }
}

// ---- launcher ---------------------------------------------------------------
extern "C" void kernel_launch(void* const* d_in, const int* in_sizes, int n_in,
                              void* d_out, int out_size, void* d_ws, size_t ws_size,
                              hipStream_t stream) {
  (void)in_sizes; (void)n_in; (void)out_size; (void)ws_size;
  const float* x    = (const float*)d_in[0];
  const float* ln1g = (const float*)d_in[1];
  const float* ln1b = (const float*)d_in[2];
  const float* ln2g = (const float*)d_in[3];
  const float* ln2b = (const float*)d_in[4];
  const float* amk  = (const float*)d_in[5];
  const float* amv  = (const float*)d_in[6];
  const float* amr  = (const float*)d_in[7];
  const float* tdec = (const float*)d_in[8];
  const float* tfaa = (const float*)d_in[9];
  const float* Wr   = (const float*)d_in[10];
  const float* Wk   = (const float*)d_in[11];
  const float* Wv   = (const float*)d_in[12];
  const float* Wo   = (const float*)d_in[13];
  const float* lnxg = (const float*)d_in[14];
  const float* lnxb = (const float*)d_in[15];
  const float* fmk  = (const float*)d_in[16];
  const float* fmr  = (const float*)d_in[17];
  const float* Wfk  = (const float*)d_in[18];
  const float* Wfr  = (const float*)d_in[19];
  const float* Wfv  = (const float*)d_in[20];

  char* ws = (char*)d_ws;
  const size_t MB = 1ull << 20;
  u16* WR  = (u16*)(ws + 0 * MB);
  u16* WK  = (u16*)(ws + 8 * MB);
  u16* WV  = (u16*)(ws + 16 * MB);
  u16* WO  = (u16*)(ws + 24 * MB);
  u16* WFR = (u16*)(ws + 32 * MB);
  u16* WFK = (u16*)(ws + 40 * MB);
  u16* WFV = (u16*)(ws + 68 * MB);
  u16* H1  = (u16*)(ws + 96 * MB);
  u16* XR  = (u16*)(ws + 128 * MB);
  u16* XK  = (u16*)(ws + 160 * MB);
  u16* XV  = (u16*)(ws + 192 * MB);
  float* WBT = (float*)(ws + 224 * MB);
  float* WKT = (float*)(ws + 224 * MB + 65536);
  float* WSP = (float*)(ws + 224 * MB + 131072);
  float* SCb = (float*)(ws + 0 * MB);
  u16* STTb  = (u16*)(ws + 8 * MB);
  u16* RB   = H1;
  u16* KB   = XR;
  u16* VB   = XK;
  u16* XA   = XV;
  u16* XAN  = H1;
  u16* H2   = XV;
  u16* XK2  = WR;
  u16* XR2  = H1;
  u16* SR   = XR;
  u16* KFH  = XK;                    // (4096, 7168) bf16 M-half = 56 MB (160-216)
  float* OUT = (float*)d_out;

  dim3 blk(256), gblk(512);
  wcvt_t<<<dim3(64, 64), blk, 0, stream>>>(Wr, WR, 2048, 2048, 0);
  wcvt_t<<<dim3(64, 64), blk, 0, stream>>>(Wk, WK, 2048, 2048, 0);
  wcvt_t<<<dim3(64, 64), blk, 0, stream>>>(Wv, WV, 2048, 2048, 0);
  wcvt_t<<<dim3(64, 64), blk, 0, stream>>>(Wo, WO, 2048, 2048, 0);
  wcvt_t<<<dim3(64, 64), blk, 0, stream>>>(Wfr, WFR, 2048, 2048, 0);
  wcvt_t<<<dim3(224, 64), blk, 0, stream>>>(Wfk, WFK, 2048, 7168, 0);
  wcvt_t<<<dim3(64, 224), blk, 0, stream>>>(Wfv, WFV, 7168, 2048, 0);

  // ---- attention branch ----
  ln_rows<<<8192, blk, 0, stream>>>(x, ln1g, ln1b, H1);
  mix3<<<8192, blk, 0, stream>>>(H1, amk, amv, amr, XK, XV, XR);
  gemm5<0><<<512, gblk, 0, stream>>>(XR, WR, RB, nullptr, nullptr, 2048, 2048, 2048, 2048, 8);
  gemm5<0><<<512, gblk, 0, stream>>>(XK, WK, KB, nullptr, nullptr, 2048, 2048, 2048, 2048, 8);
  gemm5<0><<<512, gblk, 0, stream>>>(XV, WV, VB, nullptr, nullptr, 2048, 2048, 2048, 2048, 8);

  wtabs_k<<<32, 512, 0, stream>>>(tdec, WBT, WKT, WSP);
  kvsum_m<<<512, blk, 0, stream>>>(KB, VB, WKT, SCb);
  stcomb<<<128, blk, 0, stream>>>(SCb, STTb, WSP);
  att_out_m<<<dim3(128, 8, 4), blk, 0, stream>>>(RB, KB, VB, STTb, WBT, tfaa, XA);

  gnorm<<<8192, blk, 0, stream>>>(XA, lnxg, lnxb, XAN);
  gemm5<1><<<512, gblk, 0, stream>>>(XAN, WO, OUT, x, nullptr, 2048, 2048, 2048, 2048, 8);

  // ---- FFN branch (M-split) ----
  ln_rows<<<8192, blk, 0, stream>>>(OUT, ln2g, ln2b, H2);
  mix2<<<8192, blk, 0, stream>>>(H2, fmk, fmr, XK2, XR2);
  gemm5<3><<<512, gblk, 0, stream>>>(XR2, WFR, SR, nullptr, nullptr, 2048, 2048, 2048, 2048, 8);

  for (int half = 0; half < 2; half++) {
    const u16* a_half = XK2 + (size_t)half * 4096 * 2048;
    gemm5<2><<<896, gblk, 0, stream>>>(a_half, WFK, KFH, nullptr, nullptr,
                                       7168, 2048, 2048, 2048, 28);
    gemm5<9><<<256, gblk, 0, stream>>>(KFH, WFV, OUT + (size_t)half * 4096 * 2048,
                                       nullptr, SR + (size_t)half * 4096 * 2048,
                                       2048, 7168, 7168, 7168, 8);
  }
}

// Round 20
// 1262.213 us; speedup vs baseline: 1.0266x; 1.0266x over previous
//
#include <hip/hip_runtime.h>

#define B_   4
#define TT_  2048
#define C_   2048
#define H_   32
#define S_   64
#define DF_  7168
#define TCH  512
#define NCH  4

typedef unsigned short u16;
typedef __bf16 bf16x8 __attribute__((ext_vector_type(8)));
typedef float  f32x4  __attribute__((ext_vector_type(4)));

__device__ __forceinline__ u16 f2bf(float f) {
  unsigned u = __builtin_bit_cast(unsigned, f);
  u = u + 0x7FFFu + ((u >> 16) & 1u);
  return (u16)(u >> 16);
}
__device__ __forceinline__ float bf2f(u16 v) {
  unsigned u = ((unsigned)v) << 16;
  return __builtin_bit_cast(float, u);
}

#define GLOAD16(g, l) __builtin_amdgcn_global_load_lds( \
    (const __attribute__((address_space(1))) void*)(g), \
    (__attribute__((address_space(3))) void*)(l), 16, 0, 0)

__device__ __forceinline__ void vmcnt8() { asm volatile("s_waitcnt vmcnt(8)" ::: "memory"); }
__device__ __forceinline__ void vmcnt6() { asm volatile("s_waitcnt vmcnt(6)" ::: "memory"); }
__device__ __forceinline__ void vmcnt2() { asm volatile("s_waitcnt vmcnt(2)" ::: "memory"); }
__device__ __forceinline__ void vmcnt0() { asm volatile("s_waitcnt vmcnt(0)" ::: "memory"); }

// ---- weight convert+transpose ----------------------------------------------
__global__ __launch_bounds__(256) void wcvt_t(const float* __restrict__ W,
                                              u16* __restrict__ Wt, int K, int Nfull,
                                              int n0off) {
  __shared__ alignas(16) float tile[32][33];
  int nloc = blockIdx.x * 32, k0 = blockIdx.y * 32;
  int tx = threadIdx.x & 31, ty = threadIdx.x >> 5;
  for (int r = ty; r < 32; r += 8)
    tile[r][tx] = W[(size_t)(k0 + r) * Nfull + n0off + nloc + tx];
  __syncthreads();
  for (int r = ty; r < 32; r += 8)
    Wt[(size_t)(nloc + r) * K + k0 + tx] = f2bf(tile[tx][r]);
}

// ---- layernorm over C=2048, f32 in -> bf16 out ------------------------------
__global__ __launch_bounds__(256) void ln_rows(const float* __restrict__ x,
                                               const float* __restrict__ g,
                                               const float* __restrict__ b,
                                               u16* __restrict__ out) {
  const int row = blockIdx.x;
  const float* xr = x + (size_t)row * C_;
  float v[8]; float s = 0.f, s2 = 0.f;
#pragma unroll
  for (int i = 0; i < 8; i++) { v[i] = xr[threadIdx.x + i * 256]; s += v[i]; s2 += v[i] * v[i]; }
#pragma unroll
  for (int o = 32; o > 0; o >>= 1) { s += __shfl_down(s, o); s2 += __shfl_down(s2, o); }
  __shared__ float rs[4], rs2[4];
  int wid = threadIdx.x >> 6, lane = threadIdx.x & 63;
  if (lane == 0) { rs[wid] = s; rs2[wid] = s2; }
  __syncthreads();
  s = rs[0] + rs[1] + rs[2] + rs[3];
  s2 = rs2[0] + rs2[1] + rs2[2] + rs2[3];
  float m = s * (1.f / C_);
  float var = s2 * (1.f / C_) - m * m;
  float inv = rsqrtf(var + 1e-5f);
  u16* orow = out + (size_t)row * C_;
#pragma unroll
  for (int i = 0; i < 8; i++) {
    int c = threadIdx.x + i * 256;
    orow[c] = f2bf((v[i] - m) * inv * g[c] + b[c]);
  }
}

// ---- decay tables -----------------------------------------------------------
__global__ void wtabs_k(const float* __restrict__ td, float* __restrict__ wb_tab,
                        float* __restrict__ wk_tab, float* __restrict__ wspow) {
  int h = blockIdx.x, t = threadIdx.x;
  float w = expf(-expf(td[h]));
  wb_tab[h * TCH + t] = powf(w, (float)t);
  wk_tab[h * TCH + t] = powf(w, (float)(TCH - 1 - t));
  if (t == 0) wspow[h] = powf(w, (float)TCH);
}

// ---- time-shift mixes -------------------------------------------------------
__device__ __forceinline__ void mix_body(const u16* cur, const u16* prev, bool hasp,
                                         const float* mc, u16* dst) {
  ushort4 c0 = *(const ushort4*)cur;
  ushort4 c1 = *(const ushort4*)(cur + 4);
  ushort4 p0 = {0, 0, 0, 0}, p1 = {0, 0, 0, 0};
  if (hasp) { p0 = *(const ushort4*)prev; p1 = *(const ushort4*)(prev + 4); }
  float4 mA = *(const float4*)mc;
  float4 mB = *(const float4*)(mc + 4);
  ushort4 r0, r1;
  r0.x = f2bf(bf2f(c0.x) * mA.x + bf2f(p0.x) * (1.f - mA.x));
  r0.y = f2bf(bf2f(c0.y) * mA.y + bf2f(p0.y) * (1.f - mA.y));
  r0.z = f2bf(bf2f(c0.z) * mA.z + bf2f(p0.z) * (1.f - mA.z));
  r0.w = f2bf(bf2f(c0.w) * mA.w + bf2f(p0.w) * (1.f - mA.w));
  r1.x = f2bf(bf2f(c1.x) * mB.x + bf2f(p1.x) * (1.f - mB.x));
  r1.y = f2bf(bf2f(c1.y) * mB.y + bf2f(p1.y) * (1.f - mB.y));
  r1.z = f2bf(bf2f(c1.z) * mB.z + bf2f(p1.z) * (1.f - mB.z));
  r1.w = f2bf(bf2f(c1.w) * mB.w + bf2f(p1.w) * (1.f - mB.w));
  *(ushort4*)dst = r0;
  *(ushort4*)(dst + 4) = r1;
}

__global__ __launch_bounds__(256) void mix3(const u16* __restrict__ h,
                                            const float* __restrict__ mk,
                                            const float* __restrict__ mv,
                                            const float* __restrict__ mr,
                                            u16* __restrict__ xk, u16* __restrict__ xv,
                                            u16* __restrict__ xr) {
  size_t i8 = (size_t)blockIdx.x * 256 + threadIdx.x;
  size_t off = i8 * 8;
  int c0 = (int)(off & (C_ - 1));
  int row = (int)(i8 >> 8);
  bool hasp = (row & (TT_ - 1)) != 0;
  const u16* cur = h + off;
  const u16* prev = cur - C_;
  mix_body(cur, prev, hasp, mk + c0, xk + off);
  mix_body(cur, prev, hasp, mv + c0, xv + off);
  mix_body(cur, prev, hasp, mr + c0, xr + off);
}

__global__ __launch_bounds__(256) void mix2(const u16* __restrict__ h,
                                            const float* __restrict__ mk,
                                            const float* __restrict__ mr,
                                            u16* __restrict__ xk, u16* __restrict__ xr) {
  size_t i8 = (size_t)blockIdx.x * 256 + threadIdx.x;
  size_t off = i8 * 8;
  int c0 = (int)(off & (C_ - 1));
  int row = (int)(i8 >> 8);
  bool hasp = (row & (TT_ - 1)) != 0;
  const u16* cur = h + off;
  const u16* prev = cur - C_;
  mix_body(cur, prev, hasp, mk + c0, xk + off);
  mix_body(cur, prev, hasp, mr + c0, xr + off);
}

// ---- gemm4b: BM=256, BN=256, BK=64, 512 thr / 8 waves (2M x 4N), wave 128x64.
// 2 dbuf (128 KB). 4 phases, 2 barriers/tile. ALL 8 staging loads of tile t+1
// issued in phase 1 (order B0..B3,A0,A2,A1,A3); two counted waits per tile:
//  p1: vmcnt(8) -> drains current tile's A1,A3 (issued t-1 p1; ~4-phase flight)
//  p4: vmcnt(2) -> drains t+1's B+A0+A2 (issued t p1; ~3-phase flight),
//      leaving exactly {A1',A3'} outstanding (tile-boundary invariant, r14).
// BARRIER1 after p1's wait (cross-wave A1,A3); trailing barrier after p4
// (WAR on buf[p^1] + cross-wave landing of t+1's 6 loads).
// EPI: 0 = bf16 store ; 1 = f32 out = acc + res ; 2 = bf16 relu(acc)^2 ; 3 = sigmoid
template <int EPI>
__global__ __launch_bounds__(512) void gemm4(const u16* __restrict__ A,
                                             const u16* __restrict__ Bt,
                                             void* __restrict__ Cv,
                                             const float* __restrict__ res,
                                             int N, int K, int lda, int ldb, int gy) {
  __shared__ alignas(16) u16 As[2][256 * 64];
  __shared__ alignas(16) u16 Bs[2][256 * 64];
  const int nwg = gridDim.x, qq = nwg >> 3;
  const int wg = (int)(blockIdx.x & 7) * qq + (int)(blockIdx.x >> 3);
  const int bx = wg / gy, by = wg % gy;
  const int tid = threadIdx.x, w = tid >> 6, lane = tid & 63;
  const int fr = lane & 15, fq = lane >> 4;
  const int m0 = bx * 256, n0 = by * 256;
  const int wm = (w >> 2) * 128;
  const int wn = (w & 3) * 64;
  const int rowS = tid >> 3;
  const int colS = ((tid & 7) * 8) ^ ((rowS & 7) << 3);
  const u16* Ag = A + (size_t)(m0 + rowS) * lda + colS;
  const u16* Bg = Bt + (size_t)(n0 + rowS) * ldb + colS;
  const int NT = K >> 6;

  f32x4 acc[8][4];
#pragma unroll
  for (int m = 0; m < 8; m++)
#pragma unroll
    for (int n = 0; n < 4; n++) acc[m][n] = (f32x4){0.f, 0.f, 0.f, 0.f};

#define STG_A4(p, k0, j) GLOAD16(Ag + (size_t)((j) * 64) * lda + (k0), \
    (char*)As[p] + (j) * 8192 + w * 1024)
#define STG_B4(p, k0, j) GLOAD16(Bg + (size_t)((j) * 64) * ldb + (k0), \
    (char*)Bs[p] + (j) * 8192 + w * 1024)
#define RD_A4(p, kk, r) (*(const bf16x8*)((char*)As[p] + \
    ((((r) * 128) + (kk) * 64 + fq * 16) ^ (((r) & 7) << 4))))
#define RD_B4(p, kk, r) (*(const bf16x8*)((char*)Bs[p] + \
    ((((r) * 128) + (kk) * 64 + fq * 16) ^ (((r) & 7) << 4))))

  // prologue: stage tile 0 (A1,A3 last); drain all but A1,A3
  STG_B4(0, 0, 0); STG_B4(0, 0, 1); STG_B4(0, 0, 2); STG_B4(0, 0, 3);
  STG_A4(0, 0, 0); STG_A4(0, 0, 2); STG_A4(0, 0, 1); STG_A4(0, 0, 3);
  vmcnt2();
  __builtin_amdgcn_s_barrier();

  for (int t = 0; t < NT; t++) {
    const int p = t & 1;
    const bool st = (t + 1) < NT;
    const int k1 = (t + 1) << 6;
    bf16x8 av[4], bv[4];

    // ---- phase 1: kk0, M-half0; stage ALL of tile t+1 (A1,A3 last) ----
#pragma unroll
    for (int i = 0; i < 4; i++) av[i] = RD_A4(p, 0, wm + i * 16 + fr);
#pragma unroll
    for (int n = 0; n < 4; n++) bv[n] = RD_B4(p, 0, wn + n * 16 + fr);
    if (st) {
      STG_B4(p ^ 1, k1, 0); STG_B4(p ^ 1, k1, 1); STG_B4(p ^ 1, k1, 2); STG_B4(p ^ 1, k1, 3);
      STG_A4(p ^ 1, k1, 0); STG_A4(p ^ 1, k1, 2); STG_A4(p ^ 1, k1, 1); STG_A4(p ^ 1, k1, 3);
      vmcnt8();   // drains current tile's A1,A3 (issued a full tile ago)
    } else {
      vmcnt0();
    }
    __builtin_amdgcn_s_barrier();   // BARRIER1: A1,A3 landed across waves
    __builtin_amdgcn_s_setprio(1);
#pragma unroll
    for (int i = 0; i < 4; i++)
#pragma unroll
      for (int n = 0; n < 4; n++)
        acc[i][n] = __builtin_amdgcn_mfma_f32_16x16x32_bf16(av[i], bv[n], acc[i][n], 0, 0, 0);
    __builtin_amdgcn_s_setprio(0);

    // ---- phase 2: kk0, M-half1 (A1,A3; covered by BARRIER1; reuse bv) ----
#pragma unroll
    for (int i = 0; i < 4; i++) av[i] = RD_A4(p, 0, wm + 64 + i * 16 + fr);
    __builtin_amdgcn_s_setprio(1);
#pragma unroll
    for (int i = 0; i < 4; i++)
#pragma unroll
      for (int n = 0; n < 4; n++)
        acc[4 + i][n] = __builtin_amdgcn_mfma_f32_16x16x32_bf16(av[i], bv[n], acc[4 + i][n], 0, 0, 0);
    __builtin_amdgcn_s_setprio(0);

    // ---- phase 3: kk1, M-half0 ----
#pragma unroll
    for (int i = 0; i < 4; i++) av[i] = RD_A4(p, 1, wm + i * 16 + fr);
#pragma unroll
    for (int n = 0; n < 4; n++) bv[n] = RD_B4(p, 1, wn + n * 16 + fr);
    __builtin_amdgcn_s_setprio(1);
#pragma unroll
    for (int i = 0; i < 4; i++)
#pragma unroll
      for (int n = 0; n < 4; n++)
        acc[i][n] = __builtin_amdgcn_mfma_f32_16x16x32_bf16(av[i], bv[n], acc[i][n], 0, 0, 0);
    __builtin_amdgcn_s_setprio(0);

    // ---- phase 4: kk1, M-half1 (reuse bv) ----
#pragma unroll
    for (int i = 0; i < 4; i++) av[i] = RD_A4(p, 1, wm + 64 + i * 16 + fr);
    if (st) vmcnt2(); else vmcnt0();  // leave exactly {A1',A3'} outstanding
    __builtin_amdgcn_s_setprio(1);
#pragma unroll
    for (int i = 0; i < 4; i++)
#pragma unroll
      for (int n = 0; n < 4; n++)
        acc[4 + i][n] = __builtin_amdgcn_mfma_f32_16x16x32_bf16(av[i], bv[n], acc[4 + i][n], 0, 0, 0);
    __builtin_amdgcn_s_setprio(0);
    __builtin_amdgcn_s_barrier();   // TRAILING: WAR + t+1's 6 loads landed
  }
#undef STG_A4
#undef STG_B4
#undef RD_A4
#undef RD_B4

#pragma unroll
  for (int m = 0; m < 8; m++)
#pragma unroll
    for (int n = 0; n < 4; n++)
#pragma unroll
      for (int j = 0; j < 4; j++) {
        int row = m0 + wm + m * 16 + fq * 4 + j;
        int col = n0 + wn + n * 16 + fr;
        size_t idx = (size_t)row * N + col;
        float v = acc[m][n][j];
        if (EPI == 0) ((u16*)Cv)[idx] = f2bf(v);
        else if (EPI == 1) ((float*)Cv)[idx] = v + res[idx];
        else if (EPI == 2) { float r = v > 0.f ? v : 0.f; ((u16*)Cv)[idx] = f2bf(r * r); }
        else ((u16*)Cv)[idx] = f2bf(1.f / (1.f + expf(-v)));
      }
}

// ---- gemm3b: BM=128, BN=256, 3-buffer ring (depth-2), 2 phases x 16 MFMA,
// one barrier + one counted vmcnt(6) per tile (validated r17/r18).
// EPI: 9 = f32 out = out + bf16(sr)*acc
template <int EPI>
__global__ __launch_bounds__(512) void gemm3b(const u16* __restrict__ A,
                                              const u16* __restrict__ Bt,
                                              void* __restrict__ Cv,
                                              const u16* __restrict__ srp,
                                              int N, int K, int lda, int ldb, int gy) {
  __shared__ alignas(16) char smem[3 * 49152];
  const int nwg = gridDim.x, qq = nwg >> 3;
  const int wg = (int)(blockIdx.x & 7) * qq + (int)(blockIdx.x >> 3);
  const int bx = wg / gy, by = wg % gy;
  const int tid = threadIdx.x, w = tid >> 6, lane = tid & 63;
  const int fr = lane & 15, fq = lane >> 4;
  const int m0 = bx * 128, n0 = by * 256;
  const int wm = (w >> 2) * 64, wn = (w & 3) * 64;
  const int rowS = tid >> 3;
  const int colS = ((tid & 7) * 8) ^ ((rowS & 7) << 3);
  const u16* Ag = A + (size_t)(m0 + rowS) * lda + colS;
  const u16* Bg = Bt + (size_t)(n0 + rowS) * ldb + colS;
  const int NT = K >> 6;

  f32x4 acc[4][4];
#pragma unroll
  for (int m = 0; m < 4; m++)
#pragma unroll
    for (int n = 0; n < 4; n++) acc[m][n] = (f32x4){0.f, 0.f, 0.f, 0.f};

#define STG_A(buf, k0, j) GLOAD16(Ag + (size_t)((j) * 64) * lda + (k0), \
    smem + (buf) * 49152 + (j) * 8192 + w * 1024)
#define STG_B(buf, k0, j) GLOAD16(Bg + (size_t)((j) * 64) * ldb + (k0), \
    smem + (buf) * 49152 + 16384 + (j) * 8192 + w * 1024)
#define RD_A(buf, kk, m) (*(const bf16x8*)(smem + (buf) * 49152 + \
    ((((wm + (m) * 16 + fr) * 128) + (kk) * 64 + fq * 16) ^ (((wm + (m) * 16 + fr) & 7) << 4))))
#define RD_B(buf, kk, n) (*(const bf16x8*)(smem + (buf) * 49152 + 16384 + \
    ((((wn + (n) * 16 + fr) * 128) + (kk) * 64 + fq * 16) ^ (((wn + (n) * 16 + fr) & 7) << 4))))

  STG_A(0, 0, 0); STG_A(0, 0, 1);
  STG_B(0, 0, 0); STG_B(0, 0, 1); STG_B(0, 0, 2); STG_B(0, 0, 3);
  STG_A(1, 64, 0); STG_A(1, 64, 1);
  STG_B(1, 64, 0); STG_B(1, 64, 1); STG_B(1, 64, 2); STG_B(1, 64, 3);
  vmcnt6();
  __builtin_amdgcn_s_barrier();

  int bufc = 0;
  for (int t = 0; t < NT; t++) {
    int b2 = bufc + 2; if (b2 >= 3) b2 -= 3;
    const bool st = (t + 2) < NT;
    const int k2 = (t + 2) << 6;
    bf16x8 av[4], bv[4];

#pragma unroll
    for (int m = 0; m < 4; m++) av[m] = RD_A(bufc, 0, m);
#pragma unroll
    for (int n = 0; n < 4; n++) bv[n] = RD_B(bufc, 0, n);
    if (st) { STG_A(b2, k2, 0); STG_A(b2, k2, 1); STG_B(b2, k2, 0); }
    __builtin_amdgcn_s_setprio(1);
#pragma unroll
    for (int m = 0; m < 4; m++)
#pragma unroll
      for (int n = 0; n < 4; n++)
        acc[m][n] = __builtin_amdgcn_mfma_f32_16x16x32_bf16(av[m], bv[n], acc[m][n], 0, 0, 0);
    __builtin_amdgcn_s_setprio(0);

#pragma unroll
    for (int m = 0; m < 4; m++) av[m] = RD_A(bufc, 1, m);
#pragma unroll
    for (int n = 0; n < 4; n++) bv[n] = RD_B(bufc, 1, n);
    if (st) { STG_B(b2, k2, 1); STG_B(b2, k2, 2); STG_B(b2, k2, 3); }
    if (st) vmcnt6(); else vmcnt0();
    __builtin_amdgcn_s_setprio(1);
#pragma unroll
    for (int m = 0; m < 4; m++)
#pragma unroll
      for (int n = 0; n < 4; n++)
        acc[m][n] = __builtin_amdgcn_mfma_f32_16x16x32_bf16(av[m], bv[n], acc[m][n], 0, 0, 0);
    __builtin_amdgcn_s_setprio(0);
    __builtin_amdgcn_s_barrier();

    bufc = bufc + 1 == 3 ? 0 : bufc + 1;
  }
#undef STG_A
#undef STG_B
#undef RD_A
#undef RD_B

#pragma unroll
  for (int m = 0; m < 4; m++)
#pragma unroll
    for (int n = 0; n < 4; n++)
#pragma unroll
      for (int j = 0; j < 4; j++) {
        int row = m0 + wm + m * 16 + fq * 4 + j;
        int col = n0 + wn + n * 16 + fr;
        size_t idx = (size_t)row * N + col;
        float v = acc[m][n][j];
        if (EPI == 9) {
          float pvv = ((float*)Cv)[idx];
          ((float*)Cv)[idx] = pvv + bf2f(srp[idx]) * v;
        } else {
          ((u16*)Cv)[idx] = f2bf(v);
        }
      }
}

// ---- kvsum: per-chunk S_c[s][sv] = sum_t wk[t]*K[t][s]*V[t][sv]  (MFMA) -----
__global__ __launch_bounds__(256) void kvsum_m(const u16* __restrict__ K,
                                               const u16* __restrict__ V,
                                               const float* __restrict__ wk_tab,
                                               float* __restrict__ SC) {
  const int bh = blockIdx.x & 127, c = blockIdx.x >> 7;
  const int b = bh >> 5, h = bh & 31;
  const int tid = threadIdx.x, w = tid >> 6, lane = tid & 63;
  const int fr = lane & 15, fq = lane >> 4;
  const size_t chunkbase = (size_t)b * TT_ + (size_t)c * TCH;
  const u16* Kp = K + chunkbase * C_ + h * 64;
  const u16* Vp = V + chunkbase * C_ + h * 64;
  __shared__ alignas(16) u16 Kts[64 * 128];
  __shared__ alignas(16) u16 Vts[64 * 128];
  f32x4 acc[4];
#pragma unroll
  for (int n = 0; n < 4; n++) acc[n] = (f32x4){0.f, 0.f, 0.f, 0.f};

  for (int tb = 0; tb < 4; tb++) {
    __syncthreads();
    const int u = tid >> 1;
    const int tg = tb * 128 + u;
    const float wkv = wk_tab[h * TCH + tg];
#pragma unroll
    for (int i = 0; i < 4; i++) {
      int s0 = (tid & 1) * 32 + i * 8;
      uint4 dK = *(const uint4*)(Kp + (size_t)tg * C_ + s0);
      uint4 dV = *(const uint4*)(Vp + (size_t)tg * C_ + s0);
      const u16* ek = (const u16*)&dK;
      const u16* ev = (const u16*)&dV;
#pragma unroll
      for (int j = 0; j < 8; j++) {
        int s = s0 + j;
        int byte = s * 256 + u * 2;
        byte ^= (s & 7) << 4;
        *(u16*)((char*)Kts + byte) = f2bf(bf2f(ek[j]) * wkv);
        *(u16*)((char*)Vts + byte) = ev[j];
      }
    }
    __syncthreads();
#pragma unroll
    for (int kk = 0; kk < 4; kk++) {
      int rbyteA = (w * 16 + fr) * 256 + kk * 64 + fq * 16;
      rbyteA ^= (fr & 7) << 4;
      bf16x8 av = *(const bf16x8*)((char*)Kts + rbyteA);
#pragma unroll
      for (int n = 0; n < 4; n++) {
        int rbyteB = (n * 16 + fr) * 256 + kk * 64 + fq * 16;
        rbyteB ^= (fr & 7) << 4;
        bf16x8 bv = *(const bf16x8*)((char*)Vts + rbyteB);
        acc[n] = __builtin_amdgcn_mfma_f32_16x16x32_bf16(av, bv, acc[n], 0, 0, 0);
      }
    }
  }
  float* out = SC + ((size_t)c * 128 + bh) * 4096;
#pragma unroll
  for (int n = 0; n < 4; n++)
#pragma unroll
    for (int j = 0; j < 4; j++) {
      int srow = w * 16 + fq * 4 + j;
      int scol = n * 16 + fr;
      out[srow * 64 + scol] = acc[n][j];
    }
}

// ---- state combine: STt[c][s][sp] = bf16( sum_{j<c} ws^(c-1-j) SC[j][sp][s] )
__global__ __launch_bounds__(256) void stcomb(const float* __restrict__ SC,
                                              u16* __restrict__ STt,
                                              const float* __restrict__ wspow) {
  const int bh = blockIdx.x;
  const float ws = wspow[bh & 31];
  const int tid = threadIdx.x;
#pragma unroll
  for (int e = 0; e < 16; e++) {
    int idxT = e * 256 + tid;
    int s = idxT >> 6, sp = idxT & 63;
    int src = sp * 64 + s;
    float st = 0.f;
#pragma unroll
    for (int c = 0; c < 4; c++) {
      STt[((size_t)c * 128 + bh) * 4096 + idxT] = f2bf(st);
      st = ws * st + SC[((size_t)c * 128 + bh) * 4096 + src];
    }
  }
}

// ---- attention output (MFMA, batched over chunks; 34KB LDS) -----------------
__global__ __launch_bounds__(256) void att_out_m(const u16* __restrict__ R,
                                                 const u16* __restrict__ K,
                                                 const u16* __restrict__ V,
                                                 const u16* __restrict__ STt,
                                                 const float* __restrict__ wb_tab,
                                                 const float* __restrict__ u_vec,
                                                 u16* __restrict__ xa) {
  const int bh = blockIdx.x;
  const int ti = blockIdx.y;
  const int c  = blockIdx.z;
  const int b = bh >> 5, h = bh & 31;
  const int tid = threadIdx.x, w = tid >> 6, lane = tid & 63;
  const int fr = lane & 15, fq = lane >> 4;
  const int t0 = ti * 64;
  const size_t chunkbase = (size_t)b * TT_ + (size_t)c * TCH;
  const u16* Rp = R + (chunkbase + t0) * C_ + h * 64;
  const u16* Kp = K + chunkbase * C_ + h * 64;
  const u16* Vp = V + chunkbase * C_ + h * 64;

  __shared__ alignas(16) u16 Rs[64 * 64];
  __shared__ alignas(16) u16 Ks[64 * 64];
  __shared__ alignas(16) u16 Vts[64 * 64];
  __shared__ alignas(16) u16 Xs[64 * 64];
  __shared__ float wbs[512];

#pragma unroll
  for (int it = 0; it < 2; it++) {
    int r = (tid >> 3) + it * 32;
    int cb = (tid & 7) * 16;
    uint4 d = *(const uint4*)((const char*)(Rp + (size_t)r * C_) + cb);
    int byte = (r * 128 + cb) ^ ((r & 7) << 4);
    *(uint4*)((char*)Rs + byte) = d;
  }
  const u16* stg = STt + ((size_t)c * 128 + bh) * 4096;
#pragma unroll
  for (int it = 0; it < 2; it++) {
    int s = (tid >> 3) + it * 32;
    int cb = (tid & 7) * 16;
    uint4 d = *(const uint4*)((const char*)(stg + (size_t)s * 64) + cb);
    int byte = (s * 128 + cb) ^ ((s & 7) << 4);
    *(uint4*)((char*)Xs + byte) = d;
  }
  wbs[tid] = wb_tab[h * TCH + tid];
  wbs[tid + 256] = wb_tab[h * TCH + tid + 256];
  const float uh = u_vec[h];
  __syncthreads();

  f32x4 pv[4];
#pragma unroll
  for (int n = 0; n < 4; n++) pv[n] = (f32x4){0.f, 0.f, 0.f, 0.f};
#pragma unroll
  for (int kk = 0; kk < 2; kk++) {
    int rbA = ((w * 16 + fr) * 128 + kk * 64 + fq * 16) ^ ((fr & 7) << 4);
    bf16x8 av = *(const bf16x8*)((char*)Rs + rbA);
#pragma unroll
    for (int n = 0; n < 4; n++) {
      int rbB = ((n * 16 + fr) * 128 + kk * 64 + fq * 16) ^ ((fr & 7) << 4);
      bf16x8 bv = *(const bf16x8*)((char*)Xs + rbB);
      pv[n] = __builtin_amdgcn_mfma_f32_16x16x32_bf16(av, bv, pv[n], 0, 0, 0);
    }
  }
#pragma unroll
  for (int n = 0; n < 4; n++)
#pragma unroll
    for (int j = 0; j < 4; j++) {
      int tg = t0 + w * 16 + fq * 4 + j;
      pv[n][j] *= wbs[tg];
    }

  for (int ub = 0; ub <= ti; ub++) {
    const int u0 = ub * 64;
    __syncthreads();
#pragma unroll
    for (int it = 0; it < 2; it++) {
      int r = (tid >> 3) + it * 32;
      int cb = (tid & 7) * 16;
      uint4 d = *(const uint4*)((const char*)(Kp + (size_t)(u0 + r) * C_) + cb);
      int byte = (r * 128 + cb) ^ ((r & 7) << 4);
      *(uint4*)((char*)Ks + byte) = d;
    }
#pragma unroll
    for (int it = 0; it < 2; it++) {
      int u = (tid >> 3) + it * 32;
      int s0 = (tid & 7) * 8;
      uint4 d = *(const uint4*)(Vp + (size_t)(u0 + u) * C_ + s0);
      const u16* ev = (const u16*)&d;
#pragma unroll
      for (int j = 0; j < 8; j++) {
        int s = s0 + j;
        int byte = (s * 128 + u * 2) ^ ((s & 7) << 4);
        *(u16*)((char*)Vts + byte) = ev[j];
      }
    }
    __syncthreads();
    f32x4 accA[4];
#pragma unroll
    for (int n = 0; n < 4; n++) accA[n] = (f32x4){0.f, 0.f, 0.f, 0.f};
#pragma unroll
    for (int kk = 0; kk < 2; kk++) {
      int rbA = ((w * 16 + fr) * 128 + kk * 64 + fq * 16) ^ ((fr & 7) << 4);
      bf16x8 av = *(const bf16x8*)((char*)Rs + rbA);
#pragma unroll
      for (int n = 0; n < 4; n++) {
        int rbB = ((n * 16 + fr) * 128 + kk * 64 + fq * 16) ^ ((fr & 7) << 4);
        bf16x8 bv = *(const bf16x8*)((char*)Ks + rbB);
        accA[n] = __builtin_amdgcn_mfma_f32_16x16x32_bf16(av, bv, accA[n], 0, 0, 0);
      }
    }
#pragma unroll
    for (int n = 0; n < 4; n++) {
#pragma unroll
      for (int j = 0; j < 4; j++) {
        int tl = w * 16 + fq * 4 + j;
        int tg = t0 + tl;
        int u = u0 + n * 16 + fr;
        int d = tg - u;
        float f = (d > 0) ? wbs[d - 1] : ((d == 0) ? uh : 0.f);
        int byte = (tl * 128 + (n * 16 + fr) * 2) ^ ((tl & 7) << 4);
        *(u16*)((char*)Xs + byte) = f2bf(accA[n][j] * f);
      }
    }
#pragma unroll
    for (int kk = 0; kk < 2; kk++) {
      int rbA = ((w * 16 + fr) * 128 + kk * 64 + fq * 16) ^ ((fr & 7) << 4);
      bf16x8 ap = *(const bf16x8*)((char*)Xs + rbA);
#pragma unroll
      for (int n = 0; n < 4; n++) {
        int rbB = ((n * 16 + fr) * 128 + kk * 64 + fq * 16) ^ ((fr & 7) << 4);
        bf16x8 vp = *(const bf16x8*)((char*)Vts + rbB);
        pv[n] = __builtin_amdgcn_mfma_f32_16x16x32_bf16(ap, vp, pv[n], 0, 0, 0);
      }
    }
  }
  u16* xout = xa + (chunkbase + t0) * C_ + h * 64;
#pragma unroll
  for (int n = 0; n < 4; n++)
#pragma unroll
    for (int j = 0; j < 4; j++) {
      int tl = w * 16 + fq * 4 + j;
      xout[(size_t)tl * C_ + n * 16 + fr] = f2bf(pv[n][j]);
    }
}

// ---- per-head groupnorm ------------------------------------------------------
__global__ __launch_bounds__(256) void gnorm(const u16* __restrict__ xa,
                                             const float* __restrict__ g,
                                             const float* __restrict__ b,
                                             u16* __restrict__ out) {
  const int row = blockIdx.x;
  const int lane = threadIdx.x & 63, wv = threadIdx.x >> 6;
  const u16* xp = xa + (size_t)row * C_;
  u16* op = out + (size_t)row * C_;
  for (int h = wv; h < 32; h += 4) {
    float v = bf2f(xp[h * 64 + lane]) * 0.125f;
    float s = v, s2 = v * v;
#pragma unroll
    for (int o = 32; o > 0; o >>= 1) { s += __shfl_down(s, o); s2 += __shfl_down(s2, o); }
    s = __shfl(s, 0); s2 = __shfl(s2, 0);
    float m = s * (1.f / 64.f), var = s2 * (1.f / 64.f) - m * m;
    float nv = (v - m) * rsqrtf(var + 1e-5f);
    op[h * 64 + lane] = f2bf(nv * g[h * 64 + lane] + b[h * 64 + lane]);
  }
}

// ---- launcher ---------------------------------------------------------------
extern "C" void kernel_launch(void* const* d_in, const int* in_sizes, int n_in,
                              void* d_out, int out_size, void* d_ws, size_t ws_size,
                              hipStream_t stream) {
  (void)in_sizes; (void)n_in; (void)out_size; (void)ws_size;
  const float* x    = (const float*)d_in[0];
  const float* ln1g = (const float*)d_in[1];
  const float* ln1b = (const float*)d_in[2];
  const float* ln2g = (const float*)d_in[3];
  const float* ln2b = (const float*)d_in[4];
  const float* amk  = (const float*)d_in[5];
  const float* amv  = (const float*)d_in[6];
  const float* amr  = (const float*)d_in[7];
  const float* tdec = (const float*)d_in[8];
  const float* tfaa = (const float*)d_in[9];
  const float* Wr   = (const float*)d_in[10];
  const float* Wk   = (const float*)d_in[11];
  const float* Wv   = (const float*)d_in[12];
  const float* Wo   = (const float*)d_in[13];
  const float* lnxg = (const float*)d_in[14];
  const float* lnxb = (const float*)d_in[15];
  const float* fmk  = (const float*)d_in[16];
  const float* fmr  = (const float*)d_in[17];
  const float* Wfk  = (const float*)d_in[18];
  const float* Wfr  = (const float*)d_in[19];
  const float* Wfv  = (const float*)d_in[20];

  char* ws = (char*)d_ws;
  const size_t MB = 1ull << 20;
  u16* WR  = (u16*)(ws + 0 * MB);
  u16* WK  = (u16*)(ws + 8 * MB);
  u16* WV  = (u16*)(ws + 16 * MB);
  u16* WO  = (u16*)(ws + 24 * MB);
  u16* WFR = (u16*)(ws + 32 * MB);
  u16* WFK = (u16*)(ws + 40 * MB);
  u16* WFV = (u16*)(ws + 68 * MB);
  u16* H1  = (u16*)(ws + 96 * MB);
  u16* XR  = (u16*)(ws + 128 * MB);
  u16* XK  = (u16*)(ws + 160 * MB);
  u16* XV  = (u16*)(ws + 192 * MB);
  float* WBT = (float*)(ws + 224 * MB);
  float* WKT = (float*)(ws + 224 * MB + 65536);
  float* WSP = (float*)(ws + 224 * MB + 131072);
  float* SCb = (float*)(ws + 0 * MB);
  u16* STTb  = (u16*)(ws + 8 * MB);
  u16* RB   = H1;
  u16* KB   = XR;
  u16* VB   = XK;
  u16* XA   = XV;
  u16* XAN  = H1;
  u16* H2   = XV;
  u16* XK2  = WR;
  u16* XR2  = H1;
  u16* SR   = XR;
  u16* KFH  = XK;                    // (4096, 7168) bf16 M-half = 56 MB (160-216)
  float* OUT = (float*)d_out;

  dim3 blk(256), gblk(512);
  wcvt_t<<<dim3(64, 64), blk, 0, stream>>>(Wr, WR, 2048, 2048, 0);
  wcvt_t<<<dim3(64, 64), blk, 0, stream>>>(Wk, WK, 2048, 2048, 0);
  wcvt_t<<<dim3(64, 64), blk, 0, stream>>>(Wv, WV, 2048, 2048, 0);
  wcvt_t<<<dim3(64, 64), blk, 0, stream>>>(Wo, WO, 2048, 2048, 0);
  wcvt_t<<<dim3(64, 64), blk, 0, stream>>>(Wfr, WFR, 2048, 2048, 0);
  wcvt_t<<<dim3(224, 64), blk, 0, stream>>>(Wfk, WFK, 2048, 7168, 0);
  wcvt_t<<<dim3(64, 224), blk, 0, stream>>>(Wfv, WFV, 7168, 2048, 0);

  // ---- attention branch ----
  ln_rows<<<8192, blk, 0, stream>>>(x, ln1g, ln1b, H1);
  mix3<<<8192, blk, 0, stream>>>(H1, amk, amv, amr, XK, XV, XR);
  gemm4<0><<<256, gblk, 0, stream>>>(XR, WR, RB, nullptr, 2048, 2048, 2048, 2048, 8);
  gemm4<0><<<256, gblk, 0, stream>>>(XK, WK, KB, nullptr, 2048, 2048, 2048, 2048, 8);
  gemm4<0><<<256, gblk, 0, stream>>>(XV, WV, VB, nullptr, 2048, 2048, 2048, 2048, 8);

  wtabs_k<<<32, 512, 0, stream>>>(tdec, WBT, WKT, WSP);
  kvsum_m<<<512, blk, 0, stream>>>(KB, VB, WKT, SCb);
  stcomb<<<128, blk, 0, stream>>>(SCb, STTb, WSP);
  att_out_m<<<dim3(128, 8, 4), blk, 0, stream>>>(RB, KB, VB, STTb, WBT, tfaa, XA);

  gnorm<<<8192, blk, 0, stream>>>(XA, lnxg, lnxb, XAN);
  gemm4<1><<<256, gblk, 0, stream>>>(XAN, WO, OUT, x, 2048, 2048, 2048, 2048, 8);

  // ---- FFN branch (M-split) ----
  ln_rows<<<8192, blk, 0, stream>>>(OUT, ln2g, ln2b, H2);
  mix2<<<8192, blk, 0, stream>>>(H2, fmk, fmr, XK2, XR2);
  gemm4<3><<<256, gblk, 0, stream>>>(XR2, WFR, SR, nullptr, 2048, 2048, 2048, 2048, 8);

  for (int half = 0; half < 2; half++) {
    const u16* a_half = XK2 + (size_t)half * 4096 * 2048;
    gemm4<2><<<448, gblk, 0, stream>>>(a_half, WFK, KFH, nullptr,
                                       7168, 2048, 2048, 2048, 28);
    gemm3b<9><<<256, gblk, 0, stream>>>(KFH, WFV, OUT + (size_t)half * 4096 * 2048,
                                        SR + (size_t)half * 4096 * 2048,
                                        2048, 7168, 7168, 7168, 8);
  }
}

// Round 21
// 1142.806 us; speedup vs baseline: 1.1338x; 1.1045x over previous
//
#include <hip/hip_runtime.h>

#define B_   4
#define TT_  2048
#define C_   2048
#define H_   32
#define S_   64
#define DF_  7168
#define TCH  512
#define NCH  4

typedef unsigned short u16;
typedef __bf16 bf16x8 __attribute__((ext_vector_type(8)));
typedef float  f32x4  __attribute__((ext_vector_type(4)));

__device__ __forceinline__ u16 f2bf(float f) {
  unsigned u = __builtin_bit_cast(unsigned, f);
  u = u + 0x7FFFu + ((u >> 16) & 1u);
  return (u16)(u >> 16);
}
__device__ __forceinline__ float bf2f(u16 v) {
  unsigned u = ((unsigned)v) << 16;
  return __builtin_bit_cast(float, u);
}

#define GLOAD16(g, l) __builtin_amdgcn_global_load_lds( \
    (const __attribute__((address_space(1))) void*)(g), \
    (__attribute__((address_space(3))) void*)(l), 16, 0, 0)

__device__ __forceinline__ void vmcnt6() { asm volatile("s_waitcnt vmcnt(6)" ::: "memory"); }
__device__ __forceinline__ void vmcnt2() { asm volatile("s_waitcnt vmcnt(2)" ::: "memory"); }
__device__ __forceinline__ void vmcnt0() { asm volatile("s_waitcnt vmcnt(0)" ::: "memory"); }

// ---- weight convert+transpose (vectorized, 64x64 tiles) ---------------------
// W (K,Nfull) f32 -> Wt (N,K) bf16. float4 reads, LDS transpose, uint4 writes.
__global__ __launch_bounds__(256) void wcvt_t(const float* __restrict__ W,
                                              u16* __restrict__ Wt, int K, int Nfull,
                                              int n0off) {
  __shared__ alignas(16) float tile[64][65];
  const int n0 = blockIdx.x * 64, k0 = blockIdx.y * 64;
  const int r = threadIdx.x >> 4;            // 0..15
  const int c4 = (threadIdx.x & 15) * 4;     // 0..60
#pragma unroll
  for (int rr = 0; rr < 64; rr += 16) {
    float4 d = *(const float4*)&W[(size_t)(k0 + r + rr) * Nfull + n0off + n0 + c4];
    tile[r + rr][c4] = d.x; tile[r + rr][c4 + 1] = d.y;
    tile[r + rr][c4 + 2] = d.z; tile[r + rr][c4 + 3] = d.w;
  }
  __syncthreads();
  const int n = threadIdx.x >> 2;            // 0..63
  const int kg = (threadIdx.x & 3) * 16;     // 0,16,32,48
  uint4 o0, o1;
  u16* p0 = (u16*)&o0; u16* p1 = (u16*)&o1;
#pragma unroll
  for (int i = 0; i < 8; i++) p0[i] = f2bf(tile[kg + i][n]);
#pragma unroll
  for (int i = 0; i < 8; i++) p1[i] = f2bf(tile[kg + 8 + i][n]);
  u16* dst = Wt + (size_t)(n0 + n) * K + k0 + kg;
  *(uint4*)dst = o0;
  *(uint4*)(dst + 8) = o1;
}

// ---- layernorm over C=2048, f32 in -> bf16 out ------------------------------
__global__ __launch_bounds__(256) void ln_rows(const float* __restrict__ x,
                                               const float* __restrict__ g,
                                               const float* __restrict__ b,
                                               u16* __restrict__ out) {
  const int row = blockIdx.x;
  const float* xr = x + (size_t)row * C_;
  float v[8]; float s = 0.f, s2 = 0.f;
#pragma unroll
  for (int i = 0; i < 8; i++) { v[i] = xr[threadIdx.x + i * 256]; s += v[i]; s2 += v[i] * v[i]; }
#pragma unroll
  for (int o = 32; o > 0; o >>= 1) { s += __shfl_down(s, o); s2 += __shfl_down(s2, o); }
  __shared__ float rs[4], rs2[4];
  int wid = threadIdx.x >> 6, lane = threadIdx.x & 63;
  if (lane == 0) { rs[wid] = s; rs2[wid] = s2; }
  __syncthreads();
  s = rs[0] + rs[1] + rs[2] + rs[3];
  s2 = rs2[0] + rs2[1] + rs2[2] + rs2[3];
  float m = s * (1.f / C_);
  float var = s2 * (1.f / C_) - m * m;
  float inv = rsqrtf(var + 1e-5f);
  u16* orow = out + (size_t)row * C_;
#pragma unroll
  for (int i = 0; i < 8; i++) {
    int c = threadIdx.x + i * 256;
    orow[c] = f2bf((v[i] - m) * inv * g[c] + b[c]);
  }
}

// ---- decay tables -----------------------------------------------------------
__global__ void wtabs_k(const float* __restrict__ td, float* __restrict__ wb_tab,
                        float* __restrict__ wk_tab, float* __restrict__ wspow) {
  int h = blockIdx.x, t = threadIdx.x;
  float w = expf(-expf(td[h]));
  wb_tab[h * TCH + t] = powf(w, (float)t);
  wk_tab[h * TCH + t] = powf(w, (float)(TCH - 1 - t));
  if (t == 0) wspow[h] = powf(w, (float)TCH);
}

// ---- time-shift mixes -------------------------------------------------------
__device__ __forceinline__ void mix_body(const u16* cur, const u16* prev, bool hasp,
                                         const float* mc, u16* dst) {
  ushort4 c0 = *(const ushort4*)cur;
  ushort4 c1 = *(const ushort4*)(cur + 4);
  ushort4 p0 = {0, 0, 0, 0}, p1 = {0, 0, 0, 0};
  if (hasp) { p0 = *(const ushort4*)prev; p1 = *(const ushort4*)(prev + 4); }
  float4 mA = *(const float4*)mc;
  float4 mB = *(const float4*)(mc + 4);
  ushort4 r0, r1;
  r0.x = f2bf(bf2f(c0.x) * mA.x + bf2f(p0.x) * (1.f - mA.x));
  r0.y = f2bf(bf2f(c0.y) * mA.y + bf2f(p0.y) * (1.f - mA.y));
  r0.z = f2bf(bf2f(c0.z) * mA.z + bf2f(p0.z) * (1.f - mA.z));
  r0.w = f2bf(bf2f(c0.w) * mA.w + bf2f(p0.w) * (1.f - mA.w));
  r1.x = f2bf(bf2f(c1.x) * mB.x + bf2f(p1.x) * (1.f - mB.x));
  r1.y = f2bf(bf2f(c1.y) * mB.y + bf2f(p1.y) * (1.f - mB.y));
  r1.z = f2bf(bf2f(c1.z) * mB.z + bf2f(p1.z) * (1.f - mB.z));
  r1.w = f2bf(bf2f(c1.w) * mB.w + bf2f(p1.w) * (1.f - mB.w));
  *(ushort4*)dst = r0;
  *(ushort4*)(dst + 4) = r1;
}

__global__ __launch_bounds__(256) void mix3(const u16* __restrict__ h,
                                            const float* __restrict__ mk,
                                            const float* __restrict__ mv,
                                            const float* __restrict__ mr,
                                            u16* __restrict__ xk, u16* __restrict__ xv,
                                            u16* __restrict__ xr) {
  size_t i8 = (size_t)blockIdx.x * 256 + threadIdx.x;
  size_t off = i8 * 8;
  int c0 = (int)(off & (C_ - 1));
  int row = (int)(i8 >> 8);
  bool hasp = (row & (TT_ - 1)) != 0;
  const u16* cur = h + off;
  const u16* prev = cur - C_;
  mix_body(cur, prev, hasp, mk + c0, xk + off);
  mix_body(cur, prev, hasp, mv + c0, xv + off);
  mix_body(cur, prev, hasp, mr + c0, xr + off);
}

__global__ __launch_bounds__(256) void mix2(const u16* __restrict__ h,
                                            const float* __restrict__ mk,
                                            const float* __restrict__ mr,
                                            u16* __restrict__ xk, u16* __restrict__ xr) {
  size_t i8 = (size_t)blockIdx.x * 256 + threadIdx.x;
  size_t off = i8 * 8;
  int c0 = (int)(off & (C_ - 1));
  int row = (int)(i8 >> 8);
  bool hasp = (row & (TT_ - 1)) != 0;
  const u16* cur = h + off;
  const u16* prev = cur - C_;
  mix_body(cur, prev, hasp, mk + c0, xk + off);
  mix_body(cur, prev, hasp, mr + c0, xr + off);
}

// ---- gemm4 (round-18 validated): BM=256, BN=256, BK=64, 512 thr / 8 waves,
// wave tile 128x64 (acc[8][4]). 2 dbuf (128 KB). 4 phases, 2 barriers/tile.
// Staging (B0,B1),(B2,B3),(A0,A2),(A1,A3); vmcnt(2) per phase; invariant:
// {A1',A3'} outstanding at tile boundary. BARRIER1 after p1 wait; trailing
// barrier after p4 (WAR + cross-wave landing of t+1 data).
// EPI: 0 = bf16 store ; 1 = f32 out = acc + res ; 2 = bf16 relu(acc)^2 ; 3 = sigmoid
template <int EPI>
__global__ __launch_bounds__(512) void gemm4(const u16* __restrict__ A,
                                             const u16* __restrict__ Bt,
                                             void* __restrict__ Cv,
                                             const float* __restrict__ res,
                                             int N, int K, int lda, int ldb, int gy) {
  __shared__ alignas(16) u16 As[2][256 * 64];
  __shared__ alignas(16) u16 Bs[2][256 * 64];
  const int nwg = gridDim.x, qq = nwg >> 3;
  const int wg = (int)(blockIdx.x & 7) * qq + (int)(blockIdx.x >> 3);
  const int bx = wg / gy, by = wg % gy;
  const int tid = threadIdx.x, w = tid >> 6, lane = tid & 63;
  const int fr = lane & 15, fq = lane >> 4;
  const int m0 = bx * 256, n0 = by * 256;
  const int wm = (w >> 2) * 128;
  const int wn = (w & 3) * 64;
  const int rowS = tid >> 3;
  const int colS = ((tid & 7) * 8) ^ ((rowS & 7) << 3);
  const u16* Ag = A + (size_t)(m0 + rowS) * lda + colS;
  const u16* Bg = Bt + (size_t)(n0 + rowS) * ldb + colS;
  const int NT = K >> 6;

  f32x4 acc[8][4];
#pragma unroll
  for (int m = 0; m < 8; m++)
#pragma unroll
    for (int n = 0; n < 4; n++) acc[m][n] = (f32x4){0.f, 0.f, 0.f, 0.f};

#define STG_A4(p, k0, j) GLOAD16(Ag + (size_t)((j) * 64) * lda + (k0), \
    (char*)As[p] + (j) * 8192 + w * 1024)
#define STG_B4(p, k0, j) GLOAD16(Bg + (size_t)((j) * 64) * ldb + (k0), \
    (char*)Bs[p] + (j) * 8192 + w * 1024)
#define RD_A4(p, kk, r) (*(const bf16x8*)((char*)As[p] + \
    ((((r) * 128) + (kk) * 64 + fq * 16) ^ (((r) & 7) << 4))))
#define RD_B4(p, kk, r) (*(const bf16x8*)((char*)Bs[p] + \
    ((((r) * 128) + (kk) * 64 + fq * 16) ^ (((r) & 7) << 4))))

  STG_B4(0, 0, 0); STG_B4(0, 0, 1); STG_B4(0, 0, 2); STG_B4(0, 0, 3);
  STG_A4(0, 0, 0); STG_A4(0, 0, 2); STG_A4(0, 0, 1); STG_A4(0, 0, 3);
  vmcnt2();
  __builtin_amdgcn_s_barrier();

  for (int t = 0; t < NT; t++) {
    const int p = t & 1;
    const bool st = (t + 1) < NT;
    const int k1 = (t + 1) << 6;
    bf16x8 av[4], bv[4];

    // ---- phase 1: kk0, M-half0 ----
#pragma unroll
    for (int i = 0; i < 4; i++) av[i] = RD_A4(p, 0, wm + i * 16 + fr);
#pragma unroll
    for (int n = 0; n < 4; n++) bv[n] = RD_B4(p, 0, wn + n * 16 + fr);
    if (st) { STG_B4(p ^ 1, k1, 0); STG_B4(p ^ 1, k1, 1); vmcnt2(); } else vmcnt0();
    __builtin_amdgcn_s_barrier();   // BARRIER1: A1,A3 landed across waves
    __builtin_amdgcn_s_setprio(1);
#pragma unroll
    for (int i = 0; i < 4; i++)
#pragma unroll
      for (int n = 0; n < 4; n++)
        acc[i][n] = __builtin_amdgcn_mfma_f32_16x16x32_bf16(av[i], bv[n], acc[i][n], 0, 0, 0);
    __builtin_amdgcn_s_setprio(0);

    // ---- phase 2: kk0, M-half1 (reuse bv) ----
#pragma unroll
    for (int i = 0; i < 4; i++) av[i] = RD_A4(p, 0, wm + 64 + i * 16 + fr);
    if (st) { STG_B4(p ^ 1, k1, 2); STG_B4(p ^ 1, k1, 3); vmcnt2(); }
    __builtin_amdgcn_s_setprio(1);
#pragma unroll
    for (int i = 0; i < 4; i++)
#pragma unroll
      for (int n = 0; n < 4; n++)
        acc[4 + i][n] = __builtin_amdgcn_mfma_f32_16x16x32_bf16(av[i], bv[n], acc[4 + i][n], 0, 0, 0);
    __builtin_amdgcn_s_setprio(0);

    // ---- phase 3: kk1, M-half0 ----
#pragma unroll
    for (int i = 0; i < 4; i++) av[i] = RD_A4(p, 1, wm + i * 16 + fr);
#pragma unroll
    for (int n = 0; n < 4; n++) bv[n] = RD_B4(p, 1, wn + n * 16 + fr);
    if (st) { STG_A4(p ^ 1, k1, 0); STG_A4(p ^ 1, k1, 2); vmcnt2(); }
    __builtin_amdgcn_s_setprio(1);
#pragma unroll
    for (int i = 0; i < 4; i++)
#pragma unroll
      for (int n = 0; n < 4; n++)
        acc[i][n] = __builtin_amdgcn_mfma_f32_16x16x32_bf16(av[i], bv[n], acc[i][n], 0, 0, 0);
    __builtin_amdgcn_s_setprio(0);

    // ---- phase 4: kk1, M-half1 (reuse bv) ----
#pragma unroll
    for (int i = 0; i < 4; i++) av[i] = RD_A4(p, 1, wm + 64 + i * 16 + fr);
    if (st) { STG_A4(p ^ 1, k1, 1); STG_A4(p ^ 1, k1, 3); vmcnt2(); }
    __builtin_amdgcn_s_setprio(1);
#pragma unroll
    for (int i = 0; i < 4; i++)
#pragma unroll
      for (int n = 0; n < 4; n++)
        acc[4 + i][n] = __builtin_amdgcn_mfma_f32_16x16x32_bf16(av[i], bv[n], acc[4 + i][n], 0, 0, 0);
    __builtin_amdgcn_s_setprio(0);
    __builtin_amdgcn_s_barrier();   // TRAILING: WAR + cross-wave landing of t+1 data
  }
#undef STG_A4
#undef STG_B4
#undef RD_A4
#undef RD_B4

#pragma unroll
  for (int m = 0; m < 8; m++)
#pragma unroll
    for (int n = 0; n < 4; n++)
#pragma unroll
      for (int j = 0; j < 4; j++) {
        int row = m0 + wm + m * 16 + fq * 4 + j;
        int col = n0 + wn + n * 16 + fr;
        size_t idx = (size_t)row * N + col;
        float v = acc[m][n][j];
        if (EPI == 0) ((u16*)Cv)[idx] = f2bf(v);
        else if (EPI == 1) ((float*)Cv)[idx] = v + res[idx];
        else if (EPI == 2) { float r = v > 0.f ? v : 0.f; ((u16*)Cv)[idx] = f2bf(r * r); }
        else ((u16*)Cv)[idx] = f2bf(1.f / (1.f + expf(-v)));
      }
}

// ---- gemm3b: BM=128, BN=256, 3-buffer ring (depth-2), 2 phases x 16 MFMA,
// one barrier + one counted vmcnt(6) per tile (validated r17/r18).
// EPI: 9 = f32 out = out + bf16(sr)*acc
template <int EPI>
__global__ __launch_bounds__(512) void gemm3b(const u16* __restrict__ A,
                                              const u16* __restrict__ Bt,
                                              void* __restrict__ Cv,
                                              const u16* __restrict__ srp,
                                              int N, int K, int lda, int ldb, int gy) {
  __shared__ alignas(16) char smem[3 * 49152];
  const int nwg = gridDim.x, qq = nwg >> 3;
  const int wg = (int)(blockIdx.x & 7) * qq + (int)(blockIdx.x >> 3);
  const int bx = wg / gy, by = wg % gy;
  const int tid = threadIdx.x, w = tid >> 6, lane = tid & 63;
  const int fr = lane & 15, fq = lane >> 4;
  const int m0 = bx * 128, n0 = by * 256;
  const int wm = (w >> 2) * 64, wn = (w & 3) * 64;
  const int rowS = tid >> 3;
  const int colS = ((tid & 7) * 8) ^ ((rowS & 7) << 3);
  const u16* Ag = A + (size_t)(m0 + rowS) * lda + colS;
  const u16* Bg = Bt + (size_t)(n0 + rowS) * ldb + colS;
  const int NT = K >> 6;

  f32x4 acc[4][4];
#pragma unroll
  for (int m = 0; m < 4; m++)
#pragma unroll
    for (int n = 0; n < 4; n++) acc[m][n] = (f32x4){0.f, 0.f, 0.f, 0.f};

#define STG_A(buf, k0, j) GLOAD16(Ag + (size_t)((j) * 64) * lda + (k0), \
    smem + (buf) * 49152 + (j) * 8192 + w * 1024)
#define STG_B(buf, k0, j) GLOAD16(Bg + (size_t)((j) * 64) * ldb + (k0), \
    smem + (buf) * 49152 + 16384 + (j) * 8192 + w * 1024)
#define RD_A(buf, kk, m) (*(const bf16x8*)(smem + (buf) * 49152 + \
    ((((wm + (m) * 16 + fr) * 128) + (kk) * 64 + fq * 16) ^ (((wm + (m) * 16 + fr) & 7) << 4))))
#define RD_B(buf, kk, n) (*(const bf16x8*)(smem + (buf) * 49152 + 16384 + \
    ((((wn + (n) * 16 + fr) * 128) + (kk) * 64 + fq * 16) ^ (((wn + (n) * 16 + fr) & 7) << 4))))

  STG_A(0, 0, 0); STG_A(0, 0, 1);
  STG_B(0, 0, 0); STG_B(0, 0, 1); STG_B(0, 0, 2); STG_B(0, 0, 3);
  STG_A(1, 64, 0); STG_A(1, 64, 1);
  STG_B(1, 64, 0); STG_B(1, 64, 1); STG_B(1, 64, 2); STG_B(1, 64, 3);
  vmcnt6();
  __builtin_amdgcn_s_barrier();

  int bufc = 0;
  for (int t = 0; t < NT; t++) {
    int b2 = bufc + 2; if (b2 >= 3) b2 -= 3;
    const bool st = (t + 2) < NT;
    const int k2 = (t + 2) << 6;
    bf16x8 av[4], bv[4];

#pragma unroll
    for (int m = 0; m < 4; m++) av[m] = RD_A(bufc, 0, m);
#pragma unroll
    for (int n = 0; n < 4; n++) bv[n] = RD_B(bufc, 0, n);
    if (st) { STG_A(b2, k2, 0); STG_A(b2, k2, 1); STG_B(b2, k2, 0); }
    __builtin_amdgcn_s_setprio(1);
#pragma unroll
    for (int m = 0; m < 4; m++)
#pragma unroll
      for (int n = 0; n < 4; n++)
        acc[m][n] = __builtin_amdgcn_mfma_f32_16x16x32_bf16(av[m], bv[n], acc[m][n], 0, 0, 0);
    __builtin_amdgcn_s_setprio(0);

#pragma unroll
    for (int m = 0; m < 4; m++) av[m] = RD_A(bufc, 1, m);
#pragma unroll
    for (int n = 0; n < 4; n++) bv[n] = RD_B(bufc, 1, n);
    if (st) { STG_B(b2, k2, 1); STG_B(b2, k2, 2); STG_B(b2, k2, 3); }
    if (st) vmcnt6(); else vmcnt0();
    __builtin_amdgcn_s_setprio(1);
#pragma unroll
    for (int m = 0; m < 4; m++)
#pragma unroll
      for (int n = 0; n < 4; n++)
        acc[m][n] = __builtin_amdgcn_mfma_f32_16x16x32_bf16(av[m], bv[n], acc[m][n], 0, 0, 0);
    __builtin_amdgcn_s_setprio(0);
    __builtin_amdgcn_s_barrier();

    bufc = bufc + 1 == 3 ? 0 : bufc + 1;
  }
#undef STG_A
#undef STG_B
#undef RD_A
#undef RD_B

#pragma unroll
  for (int m = 0; m < 4; m++)
#pragma unroll
    for (int n = 0; n < 4; n++)
#pragma unroll
      for (int j = 0; j < 4; j++) {
        int row = m0 + wm + m * 16 + fq * 4 + j;
        int col = n0 + wn + n * 16 + fr;
        size_t idx = (size_t)row * N + col;
        float v = acc[m][n][j];
        if (EPI == 9) {
          float pvv = ((float*)Cv)[idx];
          ((float*)Cv)[idx] = pvv + bf2f(srp[idx]) * v;
        } else {
          ((u16*)Cv)[idx] = f2bf(v);
        }
      }
}

// ---- kvsum: per-chunk S_c[s][sv] = sum_t wk[t]*K[t][s]*V[t][sv]  (MFMA) -----
__global__ __launch_bounds__(256) void kvsum_m(const u16* __restrict__ K,
                                               const u16* __restrict__ V,
                                               const float* __restrict__ wk_tab,
                                               float* __restrict__ SC) {
  const int bh = blockIdx.x & 127, c = blockIdx.x >> 7;
  const int b = bh >> 5, h = bh & 31;
  const int tid = threadIdx.x, w = tid >> 6, lane = tid & 63;
  const int fr = lane & 15, fq = lane >> 4;
  const size_t chunkbase = (size_t)b * TT_ + (size_t)c * TCH;
  const u16* Kp = K + chunkbase * C_ + h * 64;
  const u16* Vp = V + chunkbase * C_ + h * 64;
  __shared__ alignas(16) u16 Kts[64 * 128];
  __shared__ alignas(16) u16 Vts[64 * 128];
  f32x4 acc[4];
#pragma unroll
  for (int n = 0; n < 4; n++) acc[n] = (f32x4){0.f, 0.f, 0.f, 0.f};

  for (int tb = 0; tb < 4; tb++) {
    __syncthreads();
    const int u = tid >> 1;
    const int tg = tb * 128 + u;
    const float wkv = wk_tab[h * TCH + tg];
#pragma unroll
    for (int i = 0; i < 4; i++) {
      int s0 = (tid & 1) * 32 + i * 8;
      uint4 dK = *(const uint4*)(Kp + (size_t)tg * C_ + s0);
      uint4 dV = *(const uint4*)(Vp + (size_t)tg * C_ + s0);
      const u16* ek = (const u16*)&dK;
      const u16* ev = (const u16*)&dV;
#pragma unroll
      for (int j = 0; j < 8; j++) {
        int s = s0 + j;
        int byte = s * 256 + u * 2;
        byte ^= (s & 7) << 4;
        *(u16*)((char*)Kts + byte) = f2bf(bf2f(ek[j]) * wkv);
        *(u16*)((char*)Vts + byte) = ev[j];
      }
    }
    __syncthreads();
#pragma unroll
    for (int kk = 0; kk < 4; kk++) {
      int rbyteA = (w * 16 + fr) * 256 + kk * 64 + fq * 16;
      rbyteA ^= (fr & 7) << 4;
      bf16x8 av = *(const bf16x8*)((char*)Kts + rbyteA);
#pragma unroll
      for (int n = 0; n < 4; n++) {
        int rbyteB = (n * 16 + fr) * 256 + kk * 64 + fq * 16;
        rbyteB ^= (fr & 7) << 4;
        bf16x8 bv = *(const bf16x8*)((char*)Vts + rbyteB);
        acc[n] = __builtin_amdgcn_mfma_f32_16x16x32_bf16(av, bv, acc[n], 0, 0, 0);
      }
    }
  }
  float* out = SC + ((size_t)c * 128 + bh) * 4096;
#pragma unroll
  for (int n = 0; n < 4; n++)
#pragma unroll
    for (int j = 0; j < 4; j++) {
      int srow = w * 16 + fq * 4 + j;
      int scol = n * 16 + fr;
      out[srow * 64 + scol] = acc[n][j];
    }
}

// ---- state combine: STt[c][s][sp] = bf16( sum_{j<c} ws^(c-1-j) SC[j][sp][s] )
__global__ __launch_bounds__(256) void stcomb(const float* __restrict__ SC,
                                              u16* __restrict__ STt,
                                              const float* __restrict__ wspow) {
  const int bh = blockIdx.x;
  const float ws = wspow[bh & 31];
  const int tid = threadIdx.x;
#pragma unroll
  for (int e = 0; e < 16; e++) {
    int idxT = e * 256 + tid;
    int s = idxT >> 6, sp = idxT & 63;
    int src = sp * 64 + s;
    float st = 0.f;
#pragma unroll
    for (int c = 0; c < 4; c++) {
      STt[((size_t)c * 128 + bh) * 4096 + idxT] = f2bf(st);
      st = ws * st + SC[((size_t)c * 128 + bh) * 4096 + src];
    }
  }
}

// ---- attention output (MFMA, batched over chunks) + FUSED GROUPNORM ---------
// Each wave holds complete 64-wide rows in registers (4 regs x 16 lanes,
// same-fq group) -> row mean/var via 4x shfl_xor masks 1/2/4/8 (fr nibble).
// Writes normalized bf16 directly (xan); in-place over R is race-free: each
// block reads/writes only its own (rows, h-slice), R staged to LDS at start.
__global__ __launch_bounds__(256) void att_out_m(const u16* __restrict__ R,
                                                 const u16* __restrict__ K,
                                                 const u16* __restrict__ V,
                                                 const u16* __restrict__ STt,
                                                 const float* __restrict__ wb_tab,
                                                 const float* __restrict__ u_vec,
                                                 const float* __restrict__ lnxg,
                                                 const float* __restrict__ lnxb,
                                                 u16* __restrict__ xan) {
  const int bh = blockIdx.x;
  const int ti = blockIdx.y;
  const int c  = blockIdx.z;
  const int b = bh >> 5, h = bh & 31;
  const int tid = threadIdx.x, w = tid >> 6, lane = tid & 63;
  const int fr = lane & 15, fq = lane >> 4;
  const int t0 = ti * 64;
  const size_t chunkbase = (size_t)b * TT_ + (size_t)c * TCH;
  const u16* Rp = R + (chunkbase + t0) * C_ + h * 64;
  const u16* Kp = K + chunkbase * C_ + h * 64;
  const u16* Vp = V + chunkbase * C_ + h * 64;

  __shared__ alignas(16) u16 Rs[64 * 64];
  __shared__ alignas(16) u16 Ks[64 * 64];
  __shared__ alignas(16) u16 Vts[64 * 64];
  __shared__ alignas(16) u16 Xs[64 * 64];
  __shared__ float wbs[512];

#pragma unroll
  for (int it = 0; it < 2; it++) {
    int r = (tid >> 3) + it * 32;
    int cb = (tid & 7) * 16;
    uint4 d = *(const uint4*)((const char*)(Rp + (size_t)r * C_) + cb);
    int byte = (r * 128 + cb) ^ ((r & 7) << 4);
    *(uint4*)((char*)Rs + byte) = d;
  }
  const u16* stg = STt + ((size_t)c * 128 + bh) * 4096;
#pragma unroll
  for (int it = 0; it < 2; it++) {
    int s = (tid >> 3) + it * 32;
    int cb = (tid & 7) * 16;
    uint4 d = *(const uint4*)((const char*)(stg + (size_t)s * 64) + cb);
    int byte = (s * 128 + cb) ^ ((s & 7) << 4);
    *(uint4*)((char*)Xs + byte) = d;
  }
  wbs[tid] = wb_tab[h * TCH + tid];
  wbs[tid + 256] = wb_tab[h * TCH + tid + 256];
  const float uh = u_vec[h];
  __syncthreads();

  f32x4 pv[4];
#pragma unroll
  for (int n = 0; n < 4; n++) pv[n] = (f32x4){0.f, 0.f, 0.f, 0.f};
#pragma unroll
  for (int kk = 0; kk < 2; kk++) {
    int rbA = ((w * 16 + fr) * 128 + kk * 64 + fq * 16) ^ ((fr & 7) << 4);
    bf16x8 av = *(const bf16x8*)((char*)Rs + rbA);
#pragma unroll
    for (int n = 0; n < 4; n++) {
      int rbB = ((n * 16 + fr) * 128 + kk * 64 + fq * 16) ^ ((fr & 7) << 4);
      bf16x8 bv = *(const bf16x8*)((char*)Xs + rbB);
      pv[n] = __builtin_amdgcn_mfma_f32_16x16x32_bf16(av, bv, pv[n], 0, 0, 0);
    }
  }
#pragma unroll
  for (int n = 0; n < 4; n++)
#pragma unroll
    for (int j = 0; j < 4; j++) {
      int tg = t0 + w * 16 + fq * 4 + j;
      pv[n][j] *= wbs[tg];
    }

  for (int ub = 0; ub <= ti; ub++) {
    const int u0 = ub * 64;
    __syncthreads();
#pragma unroll
    for (int it = 0; it < 2; it++) {
      int r = (tid >> 3) + it * 32;
      int cb = (tid & 7) * 16;
      uint4 d = *(const uint4*)((const char*)(Kp + (size_t)(u0 + r) * C_) + cb);
      int byte = (r * 128 + cb) ^ ((r & 7) << 4);
      *(uint4*)((char*)Ks + byte) = d;
    }
#pragma unroll
    for (int it = 0; it < 2; it++) {
      int u = (tid >> 3) + it * 32;
      int s0 = (tid & 7) * 8;
      uint4 d = *(const uint4*)(Vp + (size_t)(u0 + u) * C_ + s0);
      const u16* ev = (const u16*)&d;
#pragma unroll
      for (int j = 0; j < 8; j++) {
        int s = s0 + j;
        int byte = (s * 128 + u * 2) ^ ((s & 7) << 4);
        *(u16*)((char*)Vts + byte) = ev[j];
      }
    }
    __syncthreads();
    f32x4 accA[4];
#pragma unroll
    for (int n = 0; n < 4; n++) accA[n] = (f32x4){0.f, 0.f, 0.f, 0.f};
#pragma unroll
    for (int kk = 0; kk < 2; kk++) {
      int rbA = ((w * 16 + fr) * 128 + kk * 64 + fq * 16) ^ ((fr & 7) << 4);
      bf16x8 av = *(const bf16x8*)((char*)Rs + rbA);
#pragma unroll
      for (int n = 0; n < 4; n++) {
        int rbB = ((n * 16 + fr) * 128 + kk * 64 + fq * 16) ^ ((fr & 7) << 4);
        bf16x8 bv = *(const bf16x8*)((char*)Ks + rbB);
        accA[n] = __builtin_amdgcn_mfma_f32_16x16x32_bf16(av, bv, accA[n], 0, 0, 0);
      }
    }
#pragma unroll
    for (int n = 0; n < 4; n++) {
#pragma unroll
      for (int j = 0; j < 4; j++) {
        int tl = w * 16 + fq * 4 + j;
        int tg = t0 + tl;
        int u = u0 + n * 16 + fr;
        int d = tg - u;
        float f = (d > 0) ? wbs[d - 1] : ((d == 0) ? uh : 0.f);
        int byte = (tl * 128 + (n * 16 + fr) * 2) ^ ((tl & 7) << 4);
        *(u16*)((char*)Xs + byte) = f2bf(accA[n][j] * f);
      }
    }
#pragma unroll
    for (int kk = 0; kk < 2; kk++) {
      int rbA = ((w * 16 + fr) * 128 + kk * 64 + fq * 16) ^ ((fr & 7) << 4);
      bf16x8 ap = *(const bf16x8*)((char*)Xs + rbA);
#pragma unroll
      for (int n = 0; n < 4; n++) {
        int rbB = ((n * 16 + fr) * 128 + kk * 64 + fq * 16) ^ ((fr & 7) << 4);
        bf16x8 vp = *(const bf16x8*)((char*)Vts + rbB);
        pv[n] = __builtin_amdgcn_mfma_f32_16x16x32_bf16(ap, vp, pv[n], 0, 0, 0);
      }
    }
  }

  // ---- fused groupnorm epilogue ----
#pragma unroll
  for (int n = 0; n < 4; n++)
#pragma unroll
    for (int j = 0; j < 4; j++) pv[n][j] *= 0.125f;   // / sqrt(S)=8
  float rm[4], ri[4];
#pragma unroll
  for (int j = 0; j < 4; j++) {
    float s = pv[0][j] + pv[1][j] + pv[2][j] + pv[3][j];
    float s2 = pv[0][j] * pv[0][j] + pv[1][j] * pv[1][j] +
               pv[2][j] * pv[2][j] + pv[3][j] * pv[3][j];
#pragma unroll
    for (int o = 1; o < 16; o <<= 1) { s += __shfl_xor(s, o); s2 += __shfl_xor(s2, o); }
    float m = s * (1.f / 64.f);
    float var = s2 * (1.f / 64.f) - m * m;
    rm[j] = m;
    ri[j] = rsqrtf(var + 1e-5f);
  }
  const float* gg = lnxg + h * 64;
  const float* bb = lnxb + h * 64;
  u16* xout = xan + (chunkbase + t0) * C_ + h * 64;
#pragma unroll
  for (int n = 0; n < 4; n++)
#pragma unroll
    for (int j = 0; j < 4; j++) {
      int tl = w * 16 + fq * 4 + j;
      int col = n * 16 + fr;
      float nv = (pv[n][j] - rm[j]) * ri[j];
      xout[(size_t)tl * C_ + col] = f2bf(nv * gg[col] + bb[col]);
    }
}

// ---- launcher ---------------------------------------------------------------
extern "C" void kernel_launch(void* const* d_in, const int* in_sizes, int n_in,
                              void* d_out, int out_size, void* d_ws, size_t ws_size,
                              hipStream_t stream) {
  (void)in_sizes; (void)n_in; (void)out_size; (void)ws_size;
  const float* x    = (const float*)d_in[0];
  const float* ln1g = (const float*)d_in[1];
  const float* ln1b = (const float*)d_in[2];
  const float* ln2g = (const float*)d_in[3];
  const float* ln2b = (const float*)d_in[4];
  const float* amk  = (const float*)d_in[5];
  const float* amv  = (const float*)d_in[6];
  const float* amr  = (const float*)d_in[7];
  const float* tdec = (const float*)d_in[8];
  const float* tfaa = (const float*)d_in[9];
  const float* Wr   = (const float*)d_in[10];
  const float* Wk   = (const float*)d_in[11];
  const float* Wv   = (const float*)d_in[12];
  const float* Wo   = (const float*)d_in[13];
  const float* lnxg = (const float*)d_in[14];
  const float* lnxb = (const float*)d_in[15];
  const float* fmk  = (const float*)d_in[16];
  const float* fmr  = (const float*)d_in[17];
  const float* Wfk  = (const float*)d_in[18];
  const float* Wfr  = (const float*)d_in[19];
  const float* Wfv  = (const float*)d_in[20];

  char* ws = (char*)d_ws;
  const size_t MB = 1ull << 20;
  u16* WR  = (u16*)(ws + 0 * MB);
  u16* WK  = (u16*)(ws + 8 * MB);
  u16* WV  = (u16*)(ws + 16 * MB);
  u16* WO  = (u16*)(ws + 24 * MB);
  u16* WFR = (u16*)(ws + 32 * MB);
  u16* WFK = (u16*)(ws + 40 * MB);
  u16* WFV = (u16*)(ws + 68 * MB);
  u16* H1  = (u16*)(ws + 96 * MB);
  u16* XR  = (u16*)(ws + 128 * MB);
  u16* XK  = (u16*)(ws + 160 * MB);
  u16* XV  = (u16*)(ws + 192 * MB);
  float* WBT = (float*)(ws + 224 * MB);
  float* WKT = (float*)(ws + 224 * MB + 65536);
  float* WSP = (float*)(ws + 224 * MB + 131072);
  float* SCb = (float*)(ws + 0 * MB);
  u16* STTb  = (u16*)(ws + 8 * MB);
  u16* RB   = H1;
  u16* KB   = XR;
  u16* VB   = XK;
  u16* XAN  = H1;                    // fused gnorm writes in place over R
  u16* H2   = XV;
  u16* XK2  = WR;
  u16* XR2  = H1;
  u16* SR   = XR;
  u16* KFH  = XK;                    // (4096, 7168) bf16 M-half = 56 MB (160-216)
  float* OUT = (float*)d_out;

  dim3 blk(256), gblk(512);
  wcvt_t<<<dim3(32, 32), blk, 0, stream>>>(Wr, WR, 2048, 2048, 0);
  wcvt_t<<<dim3(32, 32), blk, 0, stream>>>(Wk, WK, 2048, 2048, 0);
  wcvt_t<<<dim3(32, 32), blk, 0, stream>>>(Wv, WV, 2048, 2048, 0);
  wcvt_t<<<dim3(32, 32), blk, 0, stream>>>(Wo, WO, 2048, 2048, 0);
  wcvt_t<<<dim3(32, 32), blk, 0, stream>>>(Wfr, WFR, 2048, 2048, 0);
  wcvt_t<<<dim3(112, 32), blk, 0, stream>>>(Wfk, WFK, 2048, 7168, 0);
  wcvt_t<<<dim3(32, 112), blk, 0, stream>>>(Wfv, WFV, 7168, 2048, 0);

  // ---- attention branch ----
  ln_rows<<<8192, blk, 0, stream>>>(x, ln1g, ln1b, H1);
  mix3<<<8192, blk, 0, stream>>>(H1, amk, amv, amr, XK, XV, XR);
  gemm4<0><<<256, gblk, 0, stream>>>(XR, WR, RB, nullptr, 2048, 2048, 2048, 2048, 8);
  gemm4<0><<<256, gblk, 0, stream>>>(XK, WK, KB, nullptr, 2048, 2048, 2048, 2048, 8);
  gemm4<0><<<256, gblk, 0, stream>>>(XV, WV, VB, nullptr, 2048, 2048, 2048, 2048, 8);

  wtabs_k<<<32, 512, 0, stream>>>(tdec, WBT, WKT, WSP);
  kvsum_m<<<512, blk, 0, stream>>>(KB, VB, WKT, SCb);
  stcomb<<<128, blk, 0, stream>>>(SCb, STTb, WSP);
  att_out_m<<<dim3(128, 8, 4), blk, 0, stream>>>(RB, KB, VB, STTb, WBT, tfaa,
                                                 lnxg, lnxb, XAN);

  gemm4<1><<<256, gblk, 0, stream>>>(XAN, WO, OUT, x, 2048, 2048, 2048, 2048, 8);

  // ---- FFN branch (M-split) ----
  ln_rows<<<8192, blk, 0, stream>>>(OUT, ln2g, ln2b, H2);
  mix2<<<8192, blk, 0, stream>>>(H2, fmk, fmr, XK2, XR2);
  gemm4<3><<<256, gblk, 0, stream>>>(XR2, WFR, SR, nullptr, 2048, 2048, 2048, 2048, 8);

  for (int half = 0; half < 2; half++) {
    const u16* a_half = XK2 + (size_t)half * 4096 * 2048;
    gemm4<2><<<448, gblk, 0, stream>>>(a_half, WFK, KFH, nullptr,
                                       7168, 2048, 2048, 2048, 28);
    gemm3b<9><<<256, gblk, 0, stream>>>(KFH, WFV, OUT + (size_t)half * 4096 * 2048,
                                        SR + (size_t)half * 4096 * 2048,
                                        2048, 7168, 7168, 7168, 8);
  }
}

// Round 22
// 1133.074 us; speedup vs baseline: 1.1436x; 1.0086x over previous
//
#include <hip/hip_runtime.h>

#define B_   4
#define TT_  2048
#define C_   2048
#define H_   32
#define S_   64
#define DF_  7168
#define TCH  512
#define NCH  4

typedef unsigned short u16;
typedef __bf16 bf16x8 __attribute__((ext_vector_type(8)));
typedef float  f32x4  __attribute__((ext_vector_type(4)));

__device__ __forceinline__ u16 f2bf(float f) {
  unsigned u = __builtin_bit_cast(unsigned, f);
  u = u + 0x7FFFu + ((u >> 16) & 1u);
  return (u16)(u >> 16);
}
__device__ __forceinline__ float bf2f(u16 v) {
  unsigned u = ((unsigned)v) << 16;
  return __builtin_bit_cast(float, u);
}

#define GLOAD16(g, l) __builtin_amdgcn_global_load_lds( \
    (const __attribute__((address_space(1))) void*)(g), \
    (__attribute__((address_space(3))) void*)(l), 16, 0, 0)

__device__ __forceinline__ void vmcnt6() { asm volatile("s_waitcnt vmcnt(6)" ::: "memory"); }
__device__ __forceinline__ void vmcnt2() { asm volatile("s_waitcnt vmcnt(2)" ::: "memory"); }
__device__ __forceinline__ void vmcnt0() { asm volatile("s_waitcnt vmcnt(0)" ::: "memory"); }

// ---- weight convert+transpose (vectorized, 64x64 tiles) ---------------------
__global__ __launch_bounds__(256) void wcvt_t(const float* __restrict__ W,
                                              u16* __restrict__ Wt, int K, int Nfull,
                                              int n0off) {
  __shared__ alignas(16) float tile[64][65];
  const int n0 = blockIdx.x * 64, k0 = blockIdx.y * 64;
  const int r = threadIdx.x >> 4;
  const int c4 = (threadIdx.x & 15) * 4;
#pragma unroll
  for (int rr = 0; rr < 64; rr += 16) {
    float4 d = *(const float4*)&W[(size_t)(k0 + r + rr) * Nfull + n0off + n0 + c4];
    tile[r + rr][c4] = d.x; tile[r + rr][c4 + 1] = d.y;
    tile[r + rr][c4 + 2] = d.z; tile[r + rr][c4 + 3] = d.w;
  }
  __syncthreads();
  const int n = threadIdx.x >> 2;
  const int kg = (threadIdx.x & 3) * 16;
  uint4 o0, o1;
  u16* p0 = (u16*)&o0; u16* p1 = (u16*)&o1;
#pragma unroll
  for (int i = 0; i < 8; i++) p0[i] = f2bf(tile[kg + i][n]);
#pragma unroll
  for (int i = 0; i < 8; i++) p1[i] = f2bf(tile[kg + 8 + i][n]);
  u16* dst = Wt + (size_t)(n0 + n) * K + k0 + kg;
  *(uint4*)dst = o0;
  *(uint4*)(dst + 8) = o1;
}

// ---- decay tables -----------------------------------------------------------
__global__ void wtabs_k(const float* __restrict__ td, float* __restrict__ wb_tab,
                        float* __restrict__ wk_tab, float* __restrict__ wspow) {
  int h = blockIdx.x, t = threadIdx.x;
  float w = expf(-expf(td[h]));
  wb_tab[h * TCH + t] = powf(w, (float)t);
  wk_tab[h * TCH + t] = powf(w, (float)(TCH - 1 - t));
  if (t == 0) wspow[h] = powf(w, (float)TCH);
}

// ---- fused layernorm + time-shift mix (h never materialized) ----------------
// Each block handles one row r: LN(x[r]) and LN(x[r-1]) recomputed in f32
// (deterministic, identical across blocks), then mixes written bf16.
__global__ __launch_bounds__(256) void ln_mix3(const float* __restrict__ x,
                                               const float* __restrict__ g,
                                               const float* __restrict__ b,
                                               const float* __restrict__ mk,
                                               const float* __restrict__ mv,
                                               const float* __restrict__ mr,
                                               u16* __restrict__ xk,
                                               u16* __restrict__ xv,
                                               u16* __restrict__ xr) {
  const int row = blockIdx.x;
  const bool hasp = (row & (TT_ - 1)) != 0;
  const float* xc = x + (size_t)row * C_;
  const float* xp = xc - C_;
  const int c0 = threadIdx.x * 8;
  float v[8], p[8];
  {
    float4 a0 = *(const float4*)&xc[c0], a1 = *(const float4*)&xc[c0 + 4];
    v[0] = a0.x; v[1] = a0.y; v[2] = a0.z; v[3] = a0.w;
    v[4] = a1.x; v[5] = a1.y; v[6] = a1.z; v[7] = a1.w;
    if (hasp) {
      float4 b0 = *(const float4*)&xp[c0], b1 = *(const float4*)&xp[c0 + 4];
      p[0] = b0.x; p[1] = b0.y; p[2] = b0.z; p[3] = b0.w;
      p[4] = b1.x; p[5] = b1.y; p[6] = b1.z; p[7] = b1.w;
    } else {
#pragma unroll
      for (int i = 0; i < 8; i++) p[i] = 0.f;
    }
  }
  float s = 0.f, s2 = 0.f, u = 0.f, u2 = 0.f;
#pragma unroll
  for (int i = 0; i < 8; i++) {
    s += v[i]; s2 += v[i] * v[i];
    u += p[i]; u2 += p[i] * p[i];
  }
#pragma unroll
  for (int o = 32; o > 0; o >>= 1) {
    s += __shfl_down(s, o); s2 += __shfl_down(s2, o);
    u += __shfl_down(u, o); u2 += __shfl_down(u2, o);
  }
  __shared__ float rs[4], rs2[4], ru[4], ru2[4];
  int wid = threadIdx.x >> 6, lane = threadIdx.x & 63;
  if (lane == 0) { rs[wid] = s; rs2[wid] = s2; ru[wid] = u; ru2[wid] = u2; }
  __syncthreads();
  s = rs[0] + rs[1] + rs[2] + rs[3]; s2 = rs2[0] + rs2[1] + rs2[2] + rs2[3];
  u = ru[0] + ru[1] + ru[2] + ru[3]; u2 = ru2[0] + ru2[1] + ru2[2] + ru2[3];
  float mC = s * (1.f / C_), iC = rsqrtf(s2 * (1.f / C_) - mC * mC + 1e-5f);
  float mP = u * (1.f / C_), iP = rsqrtf(u2 * (1.f / C_) - mP * mP + 1e-5f);
  float4 g0 = *(const float4*)&g[c0], g1 = *(const float4*)&g[c0 + 4];
  float4 b0 = *(const float4*)&b[c0], b1 = *(const float4*)&b[c0 + 4];
  float gg[8] = {g0.x, g0.y, g0.z, g0.w, g1.x, g1.y, g1.z, g1.w};
  float bb[8] = {b0.x, b0.y, b0.z, b0.w, b1.x, b1.y, b1.z, b1.w};
  float4 k0v = *(const float4*)&mk[c0], k1v = *(const float4*)&mk[c0 + 4];
  float4 v0v = *(const float4*)&mv[c0], v1v = *(const float4*)&mv[c0 + 4];
  float4 r0v = *(const float4*)&mr[c0], r1v = *(const float4*)&mr[c0 + 4];
  float km[8] = {k0v.x, k0v.y, k0v.z, k0v.w, k1v.x, k1v.y, k1v.z, k1v.w};
  float vm[8] = {v0v.x, v0v.y, v0v.z, v0v.w, v1v.x, v1v.y, v1v.z, v1v.w};
  float rm[8] = {r0v.x, r0v.y, r0v.z, r0v.w, r1v.x, r1v.y, r1v.z, r1v.w};
  ushort4 ok0, ok1, ov0, ov1, or0, or1;
  u16* pk0 = (u16*)&ok0; u16* pv0 = (u16*)&ov0; u16* pr0 = (u16*)&or0;
#pragma unroll
  for (int i = 0; i < 8; i++) {
    float hc = (v[i] - mC) * iC * gg[i] + bb[i];
    float hp = hasp ? (p[i] - mP) * iP * gg[i] + bb[i] : 0.f;
    u16 ek = f2bf(hc * km[i] + hp * (1.f - km[i]));
    u16 ev = f2bf(hc * vm[i] + hp * (1.f - vm[i]));
    u16 er = f2bf(hc * rm[i] + hp * (1.f - rm[i]));
    if (i < 4) { pk0[i] = ek; pv0[i] = ev; pr0[i] = er; }
    else { ((u16*)&ok1)[i - 4] = ek; ((u16*)&ov1)[i - 4] = ev; ((u16*)&or1)[i - 4] = er; }
  }
  size_t base = (size_t)row * C_ + c0;
  *(ushort4*)&xk[base] = ok0; *(ushort4*)&xk[base + 4] = ok1;
  *(ushort4*)&xv[base] = ov0; *(ushort4*)&xv[base + 4] = ov1;
  *(ushort4*)&xr[base] = or0; *(ushort4*)&xr[base + 4] = or1;
}

__global__ __launch_bounds__(256) void ln_mix2(const float* __restrict__ x,
                                               const float* __restrict__ g,
                                               const float* __restrict__ b,
                                               const float* __restrict__ mk,
                                               const float* __restrict__ mr,
                                               u16* __restrict__ xk,
                                               u16* __restrict__ xr) {
  const int row = blockIdx.x;
  const bool hasp = (row & (TT_ - 1)) != 0;
  const float* xc = x + (size_t)row * C_;
  const float* xp = xc - C_;
  const int c0 = threadIdx.x * 8;
  float v[8], p[8];
  {
    float4 a0 = *(const float4*)&xc[c0], a1 = *(const float4*)&xc[c0 + 4];
    v[0] = a0.x; v[1] = a0.y; v[2] = a0.z; v[3] = a0.w;
    v[4] = a1.x; v[5] = a1.y; v[6] = a1.z; v[7] = a1.w;
    if (hasp) {
      float4 b0 = *(const float4*)&xp[c0], b1 = *(const float4*)&xp[c0 + 4];
      p[0] = b0.x; p[1] = b0.y; p[2] = b0.z; p[3] = b0.w;
      p[4] = b1.x; p[5] = b1.y; p[6] = b1.z; p[7] = b1.w;
    } else {
#pragma unroll
      for (int i = 0; i < 8; i++) p[i] = 0.f;
    }
  }
  float s = 0.f, s2 = 0.f, u = 0.f, u2 = 0.f;
#pragma unroll
  for (int i = 0; i < 8; i++) {
    s += v[i]; s2 += v[i] * v[i];
    u += p[i]; u2 += p[i] * p[i];
  }
#pragma unroll
  for (int o = 32; o > 0; o >>= 1) {
    s += __shfl_down(s, o); s2 += __shfl_down(s2, o);
    u += __shfl_down(u, o); u2 += __shfl_down(u2, o);
  }
  __shared__ float rs[4], rs2[4], ru[4], ru2[4];
  int wid = threadIdx.x >> 6, lane = threadIdx.x & 63;
  if (lane == 0) { rs[wid] = s; rs2[wid] = s2; ru[wid] = u; ru2[wid] = u2; }
  __syncthreads();
  s = rs[0] + rs[1] + rs[2] + rs[3]; s2 = rs2[0] + rs2[1] + rs2[2] + rs2[3];
  u = ru[0] + ru[1] + ru[2] + ru[3]; u2 = ru2[0] + ru2[1] + ru2[2] + ru2[3];
  float mC = s * (1.f / C_), iC = rsqrtf(s2 * (1.f / C_) - mC * mC + 1e-5f);
  float mP = u * (1.f / C_), iP = rsqrtf(u2 * (1.f / C_) - mP * mP + 1e-5f);
  float4 g0 = *(const float4*)&g[c0], g1 = *(const float4*)&g[c0 + 4];
  float4 b0 = *(const float4*)&b[c0], b1 = *(const float4*)&b[c0 + 4];
  float gg[8] = {g0.x, g0.y, g0.z, g0.w, g1.x, g1.y, g1.z, g1.w};
  float bb[8] = {b0.x, b0.y, b0.z, b0.w, b1.x, b1.y, b1.z, b1.w};
  float4 k0v = *(const float4*)&mk[c0], k1v = *(const float4*)&mk[c0 + 4];
  float4 r0v = *(const float4*)&mr[c0], r1v = *(const float4*)&mr[c0 + 4];
  float km[8] = {k0v.x, k0v.y, k0v.z, k0v.w, k1v.x, k1v.y, k1v.z, k1v.w};
  float rm[8] = {r0v.x, r0v.y, r0v.z, r0v.w, r1v.x, r1v.y, r1v.z, r1v.w};
  ushort4 ok0, ok1, or0, or1;
#pragma unroll
  for (int i = 0; i < 8; i++) {
    float hc = (v[i] - mC) * iC * gg[i] + bb[i];
    float hp = hasp ? (p[i] - mP) * iP * gg[i] + bb[i] : 0.f;
    u16 ek = f2bf(hc * km[i] + hp * (1.f - km[i]));
    u16 er = f2bf(hc * rm[i] + hp * (1.f - rm[i]));
    if (i < 4) { ((u16*)&ok0)[i] = ek; ((u16*)&or0)[i] = er; }
    else { ((u16*)&ok1)[i - 4] = ek; ((u16*)&or1)[i - 4] = er; }
  }
  size_t base = (size_t)row * C_ + c0;
  *(ushort4*)&xk[base] = ok0; *(ushort4*)&xk[base + 4] = ok1;
  *(ushort4*)&xr[base] = or0; *(ushort4*)&xr[base + 4] = or1;
}

// ---- gemm4 (round-18 schedule + optional L2 grid grouping): BM=256, BN=256,
// BK=64, 512 thr / 8 waves, wave tile 128x64. 2 dbuf (128 KB). 4 phases,
// 2 barriers/tile; staging (B0,B1),(B2,B3),(A0,A2),(A1,A3) with vmcnt(2)
// per staging phase; invariant {A1',A3'} outstanding at tile boundary.
// gbx>1: remap wg -> groups of gbx bx sharing by-walk (per-XCD L2 reuse);
// requires nwg % (gbx*gy) == 0.
// EPI: 0 = bf16 store ; 1 = f32 out = acc + res ; 2 = bf16 relu(acc)^2 ; 3 = sigmoid
template <int EPI>
__global__ __launch_bounds__(512) void gemm4(const u16* __restrict__ A,
                                             const u16* __restrict__ Bt,
                                             void* __restrict__ Cv,
                                             const float* __restrict__ res,
                                             int N, int K, int lda, int ldb,
                                             int gy, int gbx) {
  __shared__ alignas(16) u16 As[2][256 * 64];
  __shared__ alignas(16) u16 Bs[2][256 * 64];
  const int nwg = gridDim.x, qq = nwg >> 3;
  const int wg = (int)(blockIdx.x & 7) * qq + (int)(blockIdx.x >> 3);
  int bx, by;
  if (gbx > 1) {
    const int span = gbx * gy;
    const int bxg = wg / span;
    const int r = wg - bxg * span;
    by = r / gbx;
    bx = bxg * gbx + (r - by * gbx);
  } else {
    bx = wg / gy;
    by = wg - bx * gy;
  }
  const int tid = threadIdx.x, w = tid >> 6, lane = tid & 63;
  const int fr = lane & 15, fq = lane >> 4;
  const int m0 = bx * 256, n0 = by * 256;
  const int wm = (w >> 2) * 128;
  const int wn = (w & 3) * 64;
  const int rowS = tid >> 3;
  const int colS = ((tid & 7) * 8) ^ ((rowS & 7) << 3);
  const u16* Ag = A + (size_t)(m0 + rowS) * lda + colS;
  const u16* Bg = Bt + (size_t)(n0 + rowS) * ldb + colS;
  const int NT = K >> 6;

  f32x4 acc[8][4];
#pragma unroll
  for (int m = 0; m < 8; m++)
#pragma unroll
    for (int n = 0; n < 4; n++) acc[m][n] = (f32x4){0.f, 0.f, 0.f, 0.f};

#define STG_A4(p, k0, j) GLOAD16(Ag + (size_t)((j) * 64) * lda + (k0), \
    (char*)As[p] + (j) * 8192 + w * 1024)
#define STG_B4(p, k0, j) GLOAD16(Bg + (size_t)((j) * 64) * ldb + (k0), \
    (char*)Bs[p] + (j) * 8192 + w * 1024)
#define RD_A4(p, kk, r) (*(const bf16x8*)((char*)As[p] + \
    ((((r) * 128) + (kk) * 64 + fq * 16) ^ (((r) & 7) << 4))))
#define RD_B4(p, kk, r) (*(const bf16x8*)((char*)Bs[p] + \
    ((((r) * 128) + (kk) * 64 + fq * 16) ^ (((r) & 7) << 4))))

  STG_B4(0, 0, 0); STG_B4(0, 0, 1); STG_B4(0, 0, 2); STG_B4(0, 0, 3);
  STG_A4(0, 0, 0); STG_A4(0, 0, 2); STG_A4(0, 0, 1); STG_A4(0, 0, 3);
  vmcnt2();
  __builtin_amdgcn_s_barrier();

  for (int t = 0; t < NT; t++) {
    const int p = t & 1;
    const bool st = (t + 1) < NT;
    const int k1 = (t + 1) << 6;
    bf16x8 av[4], bv[4];

    // ---- phase 1: kk0, M-half0 ----
#pragma unroll
    for (int i = 0; i < 4; i++) av[i] = RD_A4(p, 0, wm + i * 16 + fr);
#pragma unroll
    for (int n = 0; n < 4; n++) bv[n] = RD_B4(p, 0, wn + n * 16 + fr);
    if (st) { STG_B4(p ^ 1, k1, 0); STG_B4(p ^ 1, k1, 1); vmcnt2(); } else vmcnt0();
    __builtin_amdgcn_s_barrier();   // BARRIER1: A1,A3 landed across waves
    __builtin_amdgcn_s_setprio(1);
#pragma unroll
    for (int i = 0; i < 4; i++)
#pragma unroll
      for (int n = 0; n < 4; n++)
        acc[i][n] = __builtin_amdgcn_mfma_f32_16x16x32_bf16(av[i], bv[n], acc[i][n], 0, 0, 0);
    __builtin_amdgcn_s_setprio(0);

    // ---- phase 2: kk0, M-half1 (reuse bv) ----
#pragma unroll
    for (int i = 0; i < 4; i++) av[i] = RD_A4(p, 0, wm + 64 + i * 16 + fr);
    if (st) { STG_B4(p ^ 1, k1, 2); STG_B4(p ^ 1, k1, 3); vmcnt2(); }
    __builtin_amdgcn_s_setprio(1);
#pragma unroll
    for (int i = 0; i < 4; i++)
#pragma unroll
      for (int n = 0; n < 4; n++)
        acc[4 + i][n] = __builtin_amdgcn_mfma_f32_16x16x32_bf16(av[i], bv[n], acc[4 + i][n], 0, 0, 0);
    __builtin_amdgcn_s_setprio(0);

    // ---- phase 3: kk1, M-half0 ----
#pragma unroll
    for (int i = 0; i < 4; i++) av[i] = RD_A4(p, 1, wm + i * 16 + fr);
#pragma unroll
    for (int n = 0; n < 4; n++) bv[n] = RD_B4(p, 1, wn + n * 16 + fr);
    if (st) { STG_A4(p ^ 1, k1, 0); STG_A4(p ^ 1, k1, 2); vmcnt2(); }
    __builtin_amdgcn_s_setprio(1);
#pragma unroll
    for (int i = 0; i < 4; i++)
#pragma unroll
      for (int n = 0; n < 4; n++)
        acc[i][n] = __builtin_amdgcn_mfma_f32_16x16x32_bf16(av[i], bv[n], acc[i][n], 0, 0, 0);
    __builtin_amdgcn_s_setprio(0);

    // ---- phase 4: kk1, M-half1 (reuse bv) ----
#pragma unroll
    for (int i = 0; i < 4; i++) av[i] = RD_A4(p, 1, wm + 64 + i * 16 + fr);
    if (st) { STG_A4(p ^ 1, k1, 1); STG_A4(p ^ 1, k1, 3); vmcnt2(); }
    __builtin_amdgcn_s_setprio(1);
#pragma unroll
    for (int i = 0; i < 4; i++)
#pragma unroll
      for (int n = 0; n < 4; n++)
        acc[4 + i][n] = __builtin_amdgcn_mfma_f32_16x16x32_bf16(av[i], bv[n], acc[4 + i][n], 0, 0, 0);
    __builtin_amdgcn_s_setprio(0);
    __builtin_amdgcn_s_barrier();   // TRAILING: WAR + cross-wave landing of t+1 data
  }
#undef STG_A4
#undef STG_B4
#undef RD_A4
#undef RD_B4

#pragma unroll
  for (int m = 0; m < 8; m++)
#pragma unroll
    for (int n = 0; n < 4; n++)
#pragma unroll
      for (int j = 0; j < 4; j++) {
        int row = m0 + wm + m * 16 + fq * 4 + j;
        int col = n0 + wn + n * 16 + fr;
        size_t idx = (size_t)row * N + col;
        float v = acc[m][n][j];
        if (EPI == 0) ((u16*)Cv)[idx] = f2bf(v);
        else if (EPI == 1) ((float*)Cv)[idx] = v + res[idx];
        else if (EPI == 2) { float r = v > 0.f ? v : 0.f; ((u16*)Cv)[idx] = f2bf(r * r); }
        else ((u16*)Cv)[idx] = f2bf(1.f / (1.f + expf(-v)));
      }
}

// ---- gemm3b: BM=128, BN=256, 3-buffer ring (depth-2), 2 phases x 16 MFMA,
// one barrier + one counted vmcnt(6) per tile (validated r17/r18).
// EPI: 9 = f32 out = out + bf16(sr)*acc
template <int EPI>
__global__ __launch_bounds__(512) void gemm3b(const u16* __restrict__ A,
                                              const u16* __restrict__ Bt,
                                              void* __restrict__ Cv,
                                              const u16* __restrict__ srp,
                                              int N, int K, int lda, int ldb, int gy) {
  __shared__ alignas(16) char smem[3 * 49152];
  const int nwg = gridDim.x, qq = nwg >> 3;
  const int wg = (int)(blockIdx.x & 7) * qq + (int)(blockIdx.x >> 3);
  const int bx = wg / gy, by = wg % gy;
  const int tid = threadIdx.x, w = tid >> 6, lane = tid & 63;
  const int fr = lane & 15, fq = lane >> 4;
  const int m0 = bx * 128, n0 = by * 256;
  const int wm = (w >> 2) * 64, wn = (w & 3) * 64;
  const int rowS = tid >> 3;
  const int colS = ((tid & 7) * 8) ^ ((rowS & 7) << 3);
  const u16* Ag = A + (size_t)(m0 + rowS) * lda + colS;
  const u16* Bg = Bt + (size_t)(n0 + rowS) * ldb + colS;
  const int NT = K >> 6;

  f32x4 acc[4][4];
#pragma unroll
  for (int m = 0; m < 4; m++)
#pragma unroll
    for (int n = 0; n < 4; n++) acc[m][n] = (f32x4){0.f, 0.f, 0.f, 0.f};

#define STG_A(buf, k0, j) GLOAD16(Ag + (size_t)((j) * 64) * lda + (k0), \
    smem + (buf) * 49152 + (j) * 8192 + w * 1024)
#define STG_B(buf, k0, j) GLOAD16(Bg + (size_t)((j) * 64) * ldb + (k0), \
    smem + (buf) * 49152 + 16384 + (j) * 8192 + w * 1024)
#define RD_A(buf, kk, m) (*(const bf16x8*)(smem + (buf) * 49152 + \
    ((((wm + (m) * 16 + fr) * 128) + (kk) * 64 + fq * 16) ^ (((wm + (m) * 16 + fr) & 7) << 4))))
#define RD_B(buf, kk, n) (*(const bf16x8*)(smem + (buf) * 49152 + 16384 + \
    ((((wn + (n) * 16 + fr) * 128) + (kk) * 64 + fq * 16) ^ (((wn + (n) * 16 + fr) & 7) << 4))))

  STG_A(0, 0, 0); STG_A(0, 0, 1);
  STG_B(0, 0, 0); STG_B(0, 0, 1); STG_B(0, 0, 2); STG_B(0, 0, 3);
  STG_A(1, 64, 0); STG_A(1, 64, 1);
  STG_B(1, 64, 0); STG_B(1, 64, 1); STG_B(1, 64, 2); STG_B(1, 64, 3);
  vmcnt6();
  __builtin_amdgcn_s_barrier();

  int bufc = 0;
  for (int t = 0; t < NT; t++) {
    int b2 = bufc + 2; if (b2 >= 3) b2 -= 3;
    const bool st = (t + 2) < NT;
    const int k2 = (t + 2) << 6;
    bf16x8 av[4], bv[4];

#pragma unroll
    for (int m = 0; m < 4; m++) av[m] = RD_A(bufc, 0, m);
#pragma unroll
    for (int n = 0; n < 4; n++) bv[n] = RD_B(bufc, 0, n);
    if (st) { STG_A(b2, k2, 0); STG_A(b2, k2, 1); STG_B(b2, k2, 0); }
    __builtin_amdgcn_s_setprio(1);
#pragma unroll
    for (int m = 0; m < 4; m++)
#pragma unroll
      for (int n = 0; n < 4; n++)
        acc[m][n] = __builtin_amdgcn_mfma_f32_16x16x32_bf16(av[m], bv[n], acc[m][n], 0, 0, 0);
    __builtin_amdgcn_s_setprio(0);

#pragma unroll
    for (int m = 0; m < 4; m++) av[m] = RD_A(bufc, 1, m);
#pragma unroll
    for (int n = 0; n < 4; n++) bv[n] = RD_B(bufc, 1, n);
    if (st) { STG_B(b2, k2, 1); STG_B(b2, k2, 2); STG_B(b2, k2, 3); }
    if (st) vmcnt6(); else vmcnt0();
    __builtin_amdgcn_s_setprio(1);
#pragma unroll
    for (int m = 0; m < 4; m++)
#pragma unroll
      for (int n = 0; n < 4; n++)
        acc[m][n] = __builtin_amdgcn_mfma_f32_16x16x32_bf16(av[m], bv[n], acc[m][n], 0, 0, 0);
    __builtin_amdgcn_s_setprio(0);
    __builtin_amdgcn_s_barrier();

    bufc = bufc + 1 == 3 ? 0 : bufc + 1;
  }
#undef STG_A
#undef STG_B
#undef RD_A
#undef RD_B

#pragma unroll
  for (int m = 0; m < 4; m++)
#pragma unroll
    for (int n = 0; n < 4; n++)
#pragma unroll
      for (int j = 0; j < 4; j++) {
        int row = m0 + wm + m * 16 + fq * 4 + j;
        int col = n0 + wn + n * 16 + fr;
        size_t idx = (size_t)row * N + col;
        float v = acc[m][n][j];
        if (EPI == 9) {
          float pvv = ((float*)Cv)[idx];
          ((float*)Cv)[idx] = pvv + bf2f(srp[idx]) * v;
        } else {
          ((u16*)Cv)[idx] = f2bf(v);
        }
      }
}

// ---- kvsum: per-chunk S_c[s][sv] = sum_t wk[t]*K[t][s]*V[t][sv]  (MFMA) -----
__global__ __launch_bounds__(256) void kvsum_m(const u16* __restrict__ K,
                                               const u16* __restrict__ V,
                                               const float* __restrict__ wk_tab,
                                               float* __restrict__ SC) {
  const int bh = blockIdx.x & 127, c = blockIdx.x >> 7;
  const int b = bh >> 5, h = bh & 31;
  const int tid = threadIdx.x, w = tid >> 6, lane = tid & 63;
  const int fr = lane & 15, fq = lane >> 4;
  const size_t chunkbase = (size_t)b * TT_ + (size_t)c * TCH;
  const u16* Kp = K + chunkbase * C_ + h * 64;
  const u16* Vp = V + chunkbase * C_ + h * 64;
  __shared__ alignas(16) u16 Kts[64 * 128];
  __shared__ alignas(16) u16 Vts[64 * 128];
  f32x4 acc[4];
#pragma unroll
  for (int n = 0; n < 4; n++) acc[n] = (f32x4){0.f, 0.f, 0.f, 0.f};

  for (int tb = 0; tb < 4; tb++) {
    __syncthreads();
    const int u = tid >> 1;
    const int tg = tb * 128 + u;
    const float wkv = wk_tab[h * TCH + tg];
#pragma unroll
    for (int i = 0; i < 4; i++) {
      int s0 = (tid & 1) * 32 + i * 8;
      uint4 dK = *(const uint4*)(Kp + (size_t)tg * C_ + s0);
      uint4 dV = *(const uint4*)(Vp + (size_t)tg * C_ + s0);
      const u16* ek = (const u16*)&dK;
      const u16* ev = (const u16*)&dV;
#pragma unroll
      for (int j = 0; j < 8; j++) {
        int s = s0 + j;
        int byte = s * 256 + u * 2;
        byte ^= (s & 7) << 4;
        *(u16*)((char*)Kts + byte) = f2bf(bf2f(ek[j]) * wkv);
        *(u16*)((char*)Vts + byte) = ev[j];
      }
    }
    __syncthreads();
#pragma unroll
    for (int kk = 0; kk < 4; kk++) {
      int rbyteA = (w * 16 + fr) * 256 + kk * 64 + fq * 16;
      rbyteA ^= (fr & 7) << 4;
      bf16x8 av = *(const bf16x8*)((char*)Kts + rbyteA);
#pragma unroll
      for (int n = 0; n < 4; n++) {
        int rbyteB = (n * 16 + fr) * 256 + kk * 64 + fq * 16;
        rbyteB ^= (fr & 7) << 4;
        bf16x8 bv = *(const bf16x8*)((char*)Vts + rbyteB);
        acc[n] = __builtin_amdgcn_mfma_f32_16x16x32_bf16(av, bv, acc[n], 0, 0, 0);
      }
    }
  }
  float* out = SC + ((size_t)c * 128 + bh) * 4096;
#pragma unroll
  for (int n = 0; n < 4; n++)
#pragma unroll
    for (int j = 0; j < 4; j++) {
      int srow = w * 16 + fq * 4 + j;
      int scol = n * 16 + fr;
      out[srow * 64 + scol] = acc[n][j];
    }
}

// ---- state combine: STt[c][s][sp] = bf16( sum_{j<c} ws^(c-1-j) SC[j][sp][s] )
__global__ __launch_bounds__(256) void stcomb(const float* __restrict__ SC,
                                              u16* __restrict__ STt,
                                              const float* __restrict__ wspow) {
  const int bh = blockIdx.x;
  const float ws = wspow[bh & 31];
  const int tid = threadIdx.x;
#pragma unroll
  for (int e = 0; e < 16; e++) {
    int idxT = e * 256 + tid;
    int s = idxT >> 6, sp = idxT & 63;
    int src = sp * 64 + s;
    float st = 0.f;
#pragma unroll
    for (int c = 0; c < 4; c++) {
      STt[((size_t)c * 128 + bh) * 4096 + idxT] = f2bf(st);
      st = ws * st + SC[((size_t)c * 128 + bh) * 4096 + src];
    }
  }
}

// ---- attention output (MFMA, batched over chunks) + FUSED GROUPNORM ---------
__global__ __launch_bounds__(256) void att_out_m(const u16* __restrict__ R,
                                                 const u16* __restrict__ K,
                                                 const u16* __restrict__ V,
                                                 const u16* __restrict__ STt,
                                                 const float* __restrict__ wb_tab,
                                                 const float* __restrict__ u_vec,
                                                 const float* __restrict__ lnxg,
                                                 const float* __restrict__ lnxb,
                                                 u16* __restrict__ xan) {
  const int bh = blockIdx.x;
  const int ti = blockIdx.y;
  const int c  = blockIdx.z;
  const int b = bh >> 5, h = bh & 31;
  const int tid = threadIdx.x, w = tid >> 6, lane = tid & 63;
  const int fr = lane & 15, fq = lane >> 4;
  const int t0 = ti * 64;
  const size_t chunkbase = (size_t)b * TT_ + (size_t)c * TCH;
  const u16* Rp = R + (chunkbase + t0) * C_ + h * 64;
  const u16* Kp = K + chunkbase * C_ + h * 64;
  const u16* Vp = V + chunkbase * C_ + h * 64;

  __shared__ alignas(16) u16 Rs[64 * 64];
  __shared__ alignas(16) u16 Ks[64 * 64];
  __shared__ alignas(16) u16 Vts[64 * 64];
  __shared__ alignas(16) u16 Xs[64 * 64];
  __shared__ float wbs[512];

#pragma unroll
  for (int it = 0; it < 2; it++) {
    int r = (tid >> 3) + it * 32;
    int cb = (tid & 7) * 16;
    uint4 d = *(const uint4*)((const char*)(Rp + (size_t)r * C_) + cb);
    int byte = (r * 128 + cb) ^ ((r & 7) << 4);
    *(uint4*)((char*)Rs + byte) = d;
  }
  const u16* stg = STt + ((size_t)c * 128 + bh) * 4096;
#pragma unroll
  for (int it = 0; it < 2; it++) {
    int s = (tid >> 3) + it * 32;
    int cb = (tid & 7) * 16;
    uint4 d = *(const uint4*)((const char*)(stg + (size_t)s * 64) + cb);
    int byte = (s * 128 + cb) ^ ((s & 7) << 4);
    *(uint4*)((char*)Xs + byte) = d;
  }
  wbs[tid] = wb_tab[h * TCH + tid];
  wbs[tid + 256] = wb_tab[h * TCH + tid + 256];
  const float uh = u_vec[h];
  __syncthreads();

  f32x4 pv[4];
#pragma unroll
  for (int n = 0; n < 4; n++) pv[n] = (f32x4){0.f, 0.f, 0.f, 0.f};
#pragma unroll
  for (int kk = 0; kk < 2; kk++) {
    int rbA = ((w * 16 + fr) * 128 + kk * 64 + fq * 16) ^ ((fr & 7) << 4);
    bf16x8 av = *(const bf16x8*)((char*)Rs + rbA);
#pragma unroll
    for (int n = 0; n < 4; n++) {
      int rbB = ((n * 16 + fr) * 128 + kk * 64 + fq * 16) ^ ((fr & 7) << 4);
      bf16x8 bv = *(const bf16x8*)((char*)Xs + rbB);
      pv[n] = __builtin_amdgcn_mfma_f32_16x16x32_bf16(av, bv, pv[n], 0, 0, 0);
    }
  }
#pragma unroll
  for (int n = 0; n < 4; n++)
#pragma unroll
    for (int j = 0; j < 4; j++) {
      int tg = t0 + w * 16 + fq * 4 + j;
      pv[n][j] *= wbs[tg];
    }

  for (int ub = 0; ub <= ti; ub++) {
    const int u0 = ub * 64;
    __syncthreads();
#pragma unroll
    for (int it = 0; it < 2; it++) {
      int r = (tid >> 3) + it * 32;
      int cb = (tid & 7) * 16;
      uint4 d = *(const uint4*)((const char*)(Kp + (size_t)(u0 + r) * C_) + cb);
      int byte = (r * 128 + cb) ^ ((r & 7) << 4);
      *(uint4*)((char*)Ks + byte) = d;
    }
#pragma unroll
    for (int it = 0; it < 2; it++) {
      int u = (tid >> 3) + it * 32;
      int s0 = (tid & 7) * 8;
      uint4 d = *(const uint4*)(Vp + (size_t)(u0 + u) * C_ + s0);
      const u16* ev = (const u16*)&d;
#pragma unroll
      for (int j = 0; j < 8; j++) {
        int s = s0 + j;
        int byte = (s * 128 + u * 2) ^ ((s & 7) << 4);
        *(u16*)((char*)Vts + byte) = ev[j];
      }
    }
    __syncthreads();
    f32x4 accA[4];
#pragma unroll
    for (int n = 0; n < 4; n++) accA[n] = (f32x4){0.f, 0.f, 0.f, 0.f};
#pragma unroll
    for (int kk = 0; kk < 2; kk++) {
      int rbA = ((w * 16 + fr) * 128 + kk * 64 + fq * 16) ^ ((fr & 7) << 4);
      bf16x8 av = *(const bf16x8*)((char*)Rs + rbA);
#pragma unroll
      for (int n = 0; n < 4; n++) {
        int rbB = ((n * 16 + fr) * 128 + kk * 64 + fq * 16) ^ ((fr & 7) << 4);
        bf16x8 bv = *(const bf16x8*)((char*)Ks + rbB);
        accA[n] = __builtin_amdgcn_mfma_f32_16x16x32_bf16(av, bv, accA[n], 0, 0, 0);
      }
    }
#pragma unroll
    for (int n = 0; n < 4; n++) {
#pragma unroll
      for (int j = 0; j < 4; j++) {
        int tl = w * 16 + fq * 4 + j;
        int tg = t0 + tl;
        int u = u0 + n * 16 + fr;
        int d = tg - u;
        float f = (d > 0) ? wbs[d - 1] : ((d == 0) ? uh : 0.f);
        int byte = (tl * 128 + (n * 16 + fr) * 2) ^ ((tl & 7) << 4);
        *(u16*)((char*)Xs + byte) = f2bf(accA[n][j] * f);
      }
    }
#pragma unroll
    for (int kk = 0; kk < 2; kk++) {
      int rbA = ((w * 16 + fr) * 128 + kk * 64 + fq * 16) ^ ((fr & 7) << 4);
      bf16x8 ap = *(const bf16x8*)((char*)Xs + rbA);
#pragma unroll
      for (int n = 0; n < 4; n++) {
        int rbB = ((n * 16 + fr) * 128 + kk * 64 + fq * 16) ^ ((fr & 7) << 4);
        bf16x8 vp = *(const bf16x8*)((char*)Vts + rbB);
        pv[n] = __builtin_amdgcn_mfma_f32_16x16x32_bf16(ap, vp, pv[n], 0, 0, 0);
      }
    }
  }

  // ---- fused groupnorm epilogue ----
#pragma unroll
  for (int n = 0; n < 4; n++)
#pragma unroll
    for (int j = 0; j < 4; j++) pv[n][j] *= 0.125f;
  float rm[4], ri[4];
#pragma unroll
  for (int j = 0; j < 4; j++) {
    float s = pv[0][j] + pv[1][j] + pv[2][j] + pv[3][j];
    float s2 = pv[0][j] * pv[0][j] + pv[1][j] * pv[1][j] +
               pv[2][j] * pv[2][j] + pv[3][j] * pv[3][j];
#pragma unroll
    for (int o = 1; o < 16; o <<= 1) { s += __shfl_xor(s, o); s2 += __shfl_xor(s2, o); }
    float m = s * (1.f / 64.f);
    float var = s2 * (1.f / 64.f) - m * m;
    rm[j] = m;
    ri[j] = rsqrtf(var + 1e-5f);
  }
  const float* gg = lnxg + h * 64;
  const float* bb = lnxb + h * 64;
  u16* xout = xan + (chunkbase + t0) * C_ + h * 64;
#pragma unroll
  for (int n = 0; n < 4; n++)
#pragma unroll
    for (int j = 0; j < 4; j++) {
      int tl = w * 16 + fq * 4 + j;
      int col = n * 16 + fr;
      float nv = (pv[n][j] - rm[j]) * ri[j];
      xout[(size_t)tl * C_ + col] = f2bf(nv * gg[col] + bb[col]);
    }
}

// ---- launcher ---------------------------------------------------------------
extern "C" void kernel_launch(void* const* d_in, const int* in_sizes, int n_in,
                              void* d_out, int out_size, void* d_ws, size_t ws_size,
                              hipStream_t stream) {
  (void)in_sizes; (void)n_in; (void)out_size; (void)ws_size;
  const float* x    = (const float*)d_in[0];
  const float* ln1g = (const float*)d_in[1];
  const float* ln1b = (const float*)d_in[2];
  const float* ln2g = (const float*)d_in[3];
  const float* ln2b = (const float*)d_in[4];
  const float* amk  = (const float*)d_in[5];
  const float* amv  = (const float*)d_in[6];
  const float* amr  = (const float*)d_in[7];
  const float* tdec = (const float*)d_in[8];
  const float* tfaa = (const float*)d_in[9];
  const float* Wr   = (const float*)d_in[10];
  const float* Wk   = (const float*)d_in[11];
  const float* Wv   = (const float*)d_in[12];
  const float* Wo   = (const float*)d_in[13];
  const float* lnxg = (const float*)d_in[14];
  const float* lnxb = (const float*)d_in[15];
  const float* fmk  = (const float*)d_in[16];
  const float* fmr  = (const float*)d_in[17];
  const float* Wfk  = (const float*)d_in[18];
  const float* Wfr  = (const float*)d_in[19];
  const float* Wfv  = (const float*)d_in[20];

  char* ws = (char*)d_ws;
  const size_t MB = 1ull << 20;
  u16* WR  = (u16*)(ws + 0 * MB);
  u16* WK  = (u16*)(ws + 8 * MB);
  u16* WV  = (u16*)(ws + 16 * MB);
  u16* WO  = (u16*)(ws + 24 * MB);
  u16* WFR = (u16*)(ws + 32 * MB);
  u16* WFK = (u16*)(ws + 40 * MB);
  u16* WFV = (u16*)(ws + 68 * MB);
  u16* H1  = (u16*)(ws + 96 * MB);
  u16* XR  = (u16*)(ws + 128 * MB);
  u16* XK  = (u16*)(ws + 160 * MB);
  u16* XV  = (u16*)(ws + 192 * MB);
  float* WBT = (float*)(ws + 224 * MB);
  float* WKT = (float*)(ws + 224 * MB + 65536);
  float* WSP = (float*)(ws + 224 * MB + 131072);
  float* SCb = (float*)(ws + 0 * MB);
  u16* STTb  = (u16*)(ws + 8 * MB);
  u16* RB   = H1;
  u16* KB   = XR;
  u16* VB   = XK;
  u16* XAN  = H1;                    // fused gnorm writes in place over R
  u16* XK2  = WR;
  u16* XR2  = H1;
  u16* SR   = XR;
  u16* KFH  = XK;                    // (4096, 7168) bf16 M-half = 56 MB (160-216)
  float* OUT = (float*)d_out;

  dim3 blk(256), gblk(512);
  wcvt_t<<<dim3(32, 32), blk, 0, stream>>>(Wr, WR, 2048, 2048, 0);
  wcvt_t<<<dim3(32, 32), blk, 0, stream>>>(Wk, WK, 2048, 2048, 0);
  wcvt_t<<<dim3(32, 32), blk, 0, stream>>>(Wv, WV, 2048, 2048, 0);
  wcvt_t<<<dim3(32, 32), blk, 0, stream>>>(Wo, WO, 2048, 2048, 0);
  wcvt_t<<<dim3(32, 32), blk, 0, stream>>>(Wfr, WFR, 2048, 2048, 0);
  wcvt_t<<<dim3(112, 32), blk, 0, stream>>>(Wfk, WFK, 2048, 7168, 0);
  wcvt_t<<<dim3(32, 112), blk, 0, stream>>>(Wfv, WFV, 7168, 2048, 0);

  // ---- attention branch ----
  ln_mix3<<<8192, blk, 0, stream>>>(x, ln1g, ln1b, amk, amv, amr, XK, XV, XR);
  gemm4<0><<<256, gblk, 0, stream>>>(XR, WR, RB, nullptr, 2048, 2048, 2048, 2048, 8, 1);
  gemm4<0><<<256, gblk, 0, stream>>>(XK, WK, KB, nullptr, 2048, 2048, 2048, 2048, 8, 1);
  gemm4<0><<<256, gblk, 0, stream>>>(XV, WV, VB, nullptr, 2048, 2048, 2048, 2048, 8, 1);

  wtabs_k<<<32, 512, 0, stream>>>(tdec, WBT, WKT, WSP);
  kvsum_m<<<512, blk, 0, stream>>>(KB, VB, WKT, SCb);
  stcomb<<<128, blk, 0, stream>>>(SCb, STTb, WSP);
  att_out_m<<<dim3(128, 8, 4), blk, 0, stream>>>(RB, KB, VB, STTb, WBT, tfaa,
                                                 lnxg, lnxb, XAN);

  gemm4<1><<<256, gblk, 0, stream>>>(XAN, WO, OUT, x, 2048, 2048, 2048, 2048, 8, 1);

  // ---- FFN branch (M-split) ----
  ln_mix2<<<8192, blk, 0, stream>>>(OUT, ln2g, ln2b, fmk, fmr, XK2, XR2);
  gemm4<3><<<256, gblk, 0, stream>>>(XR2, WFR, SR, nullptr, 2048, 2048, 2048, 2048, 8, 1);

  for (int half = 0; half < 2; half++) {
    const u16* a_half = XK2 + (size_t)half * 4096 * 2048;
    gemm4<2><<<448, gblk, 0, stream>>>(a_half, WFK, KFH, nullptr,
                                       7168, 2048, 2048, 2048, 28, 8);
    gemm3b<9><<<256, gblk, 0, stream>>>(KFH, WFV, OUT + (size_t)half * 4096 * 2048,
                                        SR + (size_t)half * 4096 * 2048,
                                        2048, 7168, 7168, 7168, 8);
  }
}

// Round 23
// 1124.453 us; speedup vs baseline: 1.1523x; 1.0077x over previous
//
#include <hip/hip_runtime.h>

#define B_   4
#define TT_  2048
#define C_   2048
#define H_   32
#define S_   64
#define DF_  7168
#define TCH  512
#define NCH  4

typedef unsigned short u16;
typedef __bf16 bf16x8 __attribute__((ext_vector_type(8)));
typedef float  f32x4  __attribute__((ext_vector_type(4)));

__device__ __forceinline__ u16 f2bf(float f) {
  unsigned u = __builtin_bit_cast(unsigned, f);
  u = u + 0x7FFFu + ((u >> 16) & 1u);
  return (u16)(u >> 16);
}
__device__ __forceinline__ float bf2f(u16 v) {
  unsigned u = ((unsigned)v) << 16;
  return __builtin_bit_cast(float, u);
}

#define GLOAD16(g, l) __builtin_amdgcn_global_load_lds( \
    (const __attribute__((address_space(1))) void*)(g), \
    (__attribute__((address_space(3))) void*)(l), 16, 0, 0)

__device__ __forceinline__ void vmcnt6() { asm volatile("s_waitcnt vmcnt(6)" ::: "memory"); }
__device__ __forceinline__ void vmcnt2() { asm volatile("s_waitcnt vmcnt(2)" ::: "memory"); }
__device__ __forceinline__ void vmcnt0() { asm volatile("s_waitcnt vmcnt(0)" ::: "memory"); }

// ---- weight convert+transpose (vectorized, 64x64 tiles) ---------------------
__global__ __launch_bounds__(256) void wcvt_t(const float* __restrict__ W,
                                              u16* __restrict__ Wt, int K, int Nfull,
                                              int n0off) {
  __shared__ alignas(16) float tile[64][65];
  const int n0 = blockIdx.x * 64, k0 = blockIdx.y * 64;
  const int r = threadIdx.x >> 4;
  const int c4 = (threadIdx.x & 15) * 4;
#pragma unroll
  for (int rr = 0; rr < 64; rr += 16) {
    float4 d = *(const float4*)&W[(size_t)(k0 + r + rr) * Nfull + n0off + n0 + c4];
    tile[r + rr][c4] = d.x; tile[r + rr][c4 + 1] = d.y;
    tile[r + rr][c4 + 2] = d.z; tile[r + rr][c4 + 3] = d.w;
  }
  __syncthreads();
  const int n = threadIdx.x >> 2;
  const int kg = (threadIdx.x & 3) * 16;
  uint4 o0, o1;
  u16* p0 = (u16*)&o0; u16* p1 = (u16*)&o1;
#pragma unroll
  for (int i = 0; i < 8; i++) p0[i] = f2bf(tile[kg + i][n]);
#pragma unroll
  for (int i = 0; i < 8; i++) p1[i] = f2bf(tile[kg + 8 + i][n]);
  u16* dst = Wt + (size_t)(n0 + n) * K + k0 + kg;
  *(uint4*)dst = o0;
  *(uint4*)(dst + 8) = o1;
}

// ---- decay tables -----------------------------------------------------------
__global__ void wtabs_k(const float* __restrict__ td, float* __restrict__ wb_tab,
                        float* __restrict__ wk_tab, float* __restrict__ wspow) {
  int h = blockIdx.x, t = threadIdx.x;
  float w = expf(-expf(td[h]));
  wb_tab[h * TCH + t] = powf(w, (float)t);
  wk_tab[h * TCH + t] = powf(w, (float)(TCH - 1 - t));
  if (t == 0) wspow[h] = powf(w, (float)TCH);
}

// ---- fused layernorm + time-shift mix (h never materialized) ----------------
__global__ __launch_bounds__(256) void ln_mix3(const float* __restrict__ x,
                                               const float* __restrict__ g,
                                               const float* __restrict__ b,
                                               const float* __restrict__ mk,
                                               const float* __restrict__ mv,
                                               const float* __restrict__ mr,
                                               u16* __restrict__ xk,
                                               u16* __restrict__ xv,
                                               u16* __restrict__ xr) {
  const int row = blockIdx.x;
  const bool hasp = (row & (TT_ - 1)) != 0;
  const float* xc = x + (size_t)row * C_;
  const float* xp = xc - C_;
  const int c0 = threadIdx.x * 8;
  float v[8], p[8];
  {
    float4 a0 = *(const float4*)&xc[c0], a1 = *(const float4*)&xc[c0 + 4];
    v[0] = a0.x; v[1] = a0.y; v[2] = a0.z; v[3] = a0.w;
    v[4] = a1.x; v[5] = a1.y; v[6] = a1.z; v[7] = a1.w;
    if (hasp) {
      float4 b0 = *(const float4*)&xp[c0], b1 = *(const float4*)&xp[c0 + 4];
      p[0] = b0.x; p[1] = b0.y; p[2] = b0.z; p[3] = b0.w;
      p[4] = b1.x; p[5] = b1.y; p[6] = b1.z; p[7] = b1.w;
    } else {
#pragma unroll
      for (int i = 0; i < 8; i++) p[i] = 0.f;
    }
  }
  float s = 0.f, s2 = 0.f, u = 0.f, u2 = 0.f;
#pragma unroll
  for (int i = 0; i < 8; i++) {
    s += v[i]; s2 += v[i] * v[i];
    u += p[i]; u2 += p[i] * p[i];
  }
#pragma unroll
  for (int o = 32; o > 0; o >>= 1) {
    s += __shfl_down(s, o); s2 += __shfl_down(s2, o);
    u += __shfl_down(u, o); u2 += __shfl_down(u2, o);
  }
  __shared__ float rs[4], rs2[4], ru[4], ru2[4];
  int wid = threadIdx.x >> 6, lane = threadIdx.x & 63;
  if (lane == 0) { rs[wid] = s; rs2[wid] = s2; ru[wid] = u; ru2[wid] = u2; }
  __syncthreads();
  s = rs[0] + rs[1] + rs[2] + rs[3]; s2 = rs2[0] + rs2[1] + rs2[2] + rs2[3];
  u = ru[0] + ru[1] + ru[2] + ru[3]; u2 = ru2[0] + ru2[1] + ru2[2] + ru2[3];
  float mC = s * (1.f / C_), iC = rsqrtf(s2 * (1.f / C_) - mC * mC + 1e-5f);
  float mP = u * (1.f / C_), iP = rsqrtf(u2 * (1.f / C_) - mP * mP + 1e-5f);
  float4 g0 = *(const float4*)&g[c0], g1 = *(const float4*)&g[c0 + 4];
  float4 b0 = *(const float4*)&b[c0], b1 = *(const float4*)&b[c0 + 4];
  float gg[8] = {g0.x, g0.y, g0.z, g0.w, g1.x, g1.y, g1.z, g1.w};
  float bb[8] = {b0.x, b0.y, b0.z, b0.w, b1.x, b1.y, b1.z, b1.w};
  float4 k0v = *(const float4*)&mk[c0], k1v = *(const float4*)&mk[c0 + 4];
  float4 v0v = *(const float4*)&mv[c0], v1v = *(const float4*)&mv[c0 + 4];
  float4 r0v = *(const float4*)&mr[c0], r1v = *(const float4*)&mr[c0 + 4];
  float km[8] = {k0v.x, k0v.y, k0v.z, k0v.w, k1v.x, k1v.y, k1v.z, k1v.w};
  float vm[8] = {v0v.x, v0v.y, v0v.z, v0v.w, v1v.x, v1v.y, v1v.z, v1v.w};
  float rm[8] = {r0v.x, r0v.y, r0v.z, r0v.w, r1v.x, r1v.y, r1v.z, r1v.w};
  ushort4 ok0, ok1, ov0, ov1, or0, or1;
  u16* pk0 = (u16*)&ok0; u16* pv0 = (u16*)&ov0; u16* pr0 = (u16*)&or0;
#pragma unroll
  for (int i = 0; i < 8; i++) {
    float hc = (v[i] - mC) * iC * gg[i] + bb[i];
    float hp = hasp ? (p[i] - mP) * iP * gg[i] + bb[i] : 0.f;
    u16 ek = f2bf(hc * km[i] + hp * (1.f - km[i]));
    u16 ev = f2bf(hc * vm[i] + hp * (1.f - vm[i]));
    u16 er = f2bf(hc * rm[i] + hp * (1.f - rm[i]));
    if (i < 4) { pk0[i] = ek; pv0[i] = ev; pr0[i] = er; }
    else { ((u16*)&ok1)[i - 4] = ek; ((u16*)&ov1)[i - 4] = ev; ((u16*)&or1)[i - 4] = er; }
  }
  size_t base = (size_t)row * C_ + c0;
  *(ushort4*)&xk[base] = ok0; *(ushort4*)&xk[base + 4] = ok1;
  *(ushort4*)&xv[base] = ov0; *(ushort4*)&xv[base + 4] = ov1;
  *(ushort4*)&xr[base] = or0; *(ushort4*)&xr[base + 4] = or1;
}

__global__ __launch_bounds__(256) void ln_mix2(const float* __restrict__ x,
                                               const float* __restrict__ g,
                                               const float* __restrict__ b,
                                               const float* __restrict__ mk,
                                               const float* __restrict__ mr,
                                               u16* __restrict__ xk,
                                               u16* __restrict__ xr) {
  const int row = blockIdx.x;
  const bool hasp = (row & (TT_ - 1)) != 0;
  const float* xc = x + (size_t)row * C_;
  const float* xp = xc - C_;
  const int c0 = threadIdx.x * 8;
  float v[8], p[8];
  {
    float4 a0 = *(const float4*)&xc[c0], a1 = *(const float4*)&xc[c0 + 4];
    v[0] = a0.x; v[1] = a0.y; v[2] = a0.z; v[3] = a0.w;
    v[4] = a1.x; v[5] = a1.y; v[6] = a1.z; v[7] = a1.w;
    if (hasp) {
      float4 b0 = *(const float4*)&xp[c0], b1 = *(const float4*)&xp[c0 + 4];
      p[0] = b0.x; p[1] = b0.y; p[2] = b0.z; p[3] = b0.w;
      p[4] = b1.x; p[5] = b1.y; p[6] = b1.z; p[7] = b1.w;
    } else {
#pragma unroll
      for (int i = 0; i < 8; i++) p[i] = 0.f;
    }
  }
  float s = 0.f, s2 = 0.f, u = 0.f, u2 = 0.f;
#pragma unroll
  for (int i = 0; i < 8; i++) {
    s += v[i]; s2 += v[i] * v[i];
    u += p[i]; u2 += p[i] * p[i];
  }
#pragma unroll
  for (int o = 32; o > 0; o >>= 1) {
    s += __shfl_down(s, o); s2 += __shfl_down(s2, o);
    u += __shfl_down(u, o); u2 += __shfl_down(u2, o);
  }
  __shared__ float rs[4], rs2[4], ru[4], ru2[4];
  int wid = threadIdx.x >> 6, lane = threadIdx.x & 63;
  if (lane == 0) { rs[wid] = s; rs2[wid] = s2; ru[wid] = u; ru2[wid] = u2; }
  __syncthreads();
  s = rs[0] + rs[1] + rs[2] + rs[3]; s2 = rs2[0] + rs2[1] + rs2[2] + rs2[3];
  u = ru[0] + ru[1] + ru[2] + ru[3]; u2 = ru2[0] + ru2[1] + ru2[2] + ru2[3];
  float mC = s * (1.f / C_), iC = rsqrtf(s2 * (1.f / C_) - mC * mC + 1e-5f);
  float mP = u * (1.f / C_), iP = rsqrtf(u2 * (1.f / C_) - mP * mP + 1e-5f);
  float4 g0 = *(const float4*)&g[c0], g1 = *(const float4*)&g[c0 + 4];
  float4 b0 = *(const float4*)&b[c0], b1 = *(const float4*)&b[c0 + 4];
  float gg[8] = {g0.x, g0.y, g0.z, g0.w, g1.x, g1.y, g1.z, g1.w};
  float bb[8] = {b0.x, b0.y, b0.z, b0.w, b1.x, b1.y, b1.z, b1.w};
  float4 k0v = *(const float4*)&mk[c0], k1v = *(const float4*)&mk[c0 + 4];
  float4 r0v = *(const float4*)&mr[c0], r1v = *(const float4*)&mr[c0 + 4];
  float km[8] = {k0v.x, k0v.y, k0v.z, k0v.w, k1v.x, k1v.y, k1v.z, k1v.w};
  float rm[8] = {r0v.x, r0v.y, r0v.z, r0v.w, r1v.x, r1v.y, r1v.z, r1v.w};
  ushort4 ok0, ok1, or0, or1;
#pragma unroll
  for (int i = 0; i < 8; i++) {
    float hc = (v[i] - mC) * iC * gg[i] + bb[i];
    float hp = hasp ? (p[i] - mP) * iP * gg[i] + bb[i] : 0.f;
    u16 ek = f2bf(hc * km[i] + hp * (1.f - km[i]));
    u16 er = f2bf(hc * rm[i] + hp * (1.f - rm[i]));
    if (i < 4) { ((u16*)&ok0)[i] = ek; ((u16*)&or0)[i] = er; }
    else { ((u16*)&ok1)[i - 4] = ek; ((u16*)&or1)[i - 4] = er; }
  }
  size_t base = (size_t)row * C_ + c0;
  *(ushort4*)&xk[base] = ok0; *(ushort4*)&xk[base + 4] = ok1;
  *(ushort4*)&xr[base] = or0; *(ushort4*)&xr[base + 4] = or1;
}

// ---- gemm4 (round-18 schedule + optional L2 grid grouping) ------------------
// EPI: 0 = bf16 store ; 1 = f32 out = acc + res ; 2 = bf16 relu(acc)^2 ; 3 = sigmoid
template <int EPI>
__global__ __launch_bounds__(512) void gemm4(const u16* __restrict__ A,
                                             const u16* __restrict__ Bt,
                                             void* __restrict__ Cv,
                                             const float* __restrict__ res,
                                             int N, int K, int lda, int ldb,
                                             int gy, int gbx) {
  __shared__ alignas(16) u16 As[2][256 * 64];
  __shared__ alignas(16) u16 Bs[2][256 * 64];
  const int nwg = gridDim.x, qq = nwg >> 3;
  const int wg = (int)(blockIdx.x & 7) * qq + (int)(blockIdx.x >> 3);
  int bx, by;
  if (gbx > 1) {
    const int span = gbx * gy;
    const int bxg = wg / span;
    const int r = wg - bxg * span;
    by = r / gbx;
    bx = bxg * gbx + (r - by * gbx);
  } else {
    bx = wg / gy;
    by = wg - bx * gy;
  }
  const int tid = threadIdx.x, w = tid >> 6, lane = tid & 63;
  const int fr = lane & 15, fq = lane >> 4;
  const int m0 = bx * 256, n0 = by * 256;
  const int wm = (w >> 2) * 128;
  const int wn = (w & 3) * 64;
  const int rowS = tid >> 3;
  const int colS = ((tid & 7) * 8) ^ ((rowS & 7) << 3);
  const u16* Ag = A + (size_t)(m0 + rowS) * lda + colS;
  const u16* Bg = Bt + (size_t)(n0 + rowS) * ldb + colS;
  const int NT = K >> 6;

  f32x4 acc[8][4];
#pragma unroll
  for (int m = 0; m < 8; m++)
#pragma unroll
    for (int n = 0; n < 4; n++) acc[m][n] = (f32x4){0.f, 0.f, 0.f, 0.f};

#define STG_A4(p, k0, j) GLOAD16(Ag + (size_t)((j) * 64) * lda + (k0), \
    (char*)As[p] + (j) * 8192 + w * 1024)
#define STG_B4(p, k0, j) GLOAD16(Bg + (size_t)((j) * 64) * ldb + (k0), \
    (char*)Bs[p] + (j) * 8192 + w * 1024)
#define RD_A4(p, kk, r) (*(const bf16x8*)((char*)As[p] + \
    ((((r) * 128) + (kk) * 64 + fq * 16) ^ (((r) & 7) << 4))))
#define RD_B4(p, kk, r) (*(const bf16x8*)((char*)Bs[p] + \
    ((((r) * 128) + (kk) * 64 + fq * 16) ^ (((r) & 7) << 4))))

  STG_B4(0, 0, 0); STG_B4(0, 0, 1); STG_B4(0, 0, 2); STG_B4(0, 0, 3);
  STG_A4(0, 0, 0); STG_A4(0, 0, 2); STG_A4(0, 0, 1); STG_A4(0, 0, 3);
  vmcnt2();
  __builtin_amdgcn_s_barrier();

  for (int t = 0; t < NT; t++) {
    const int p = t & 1;
    const bool st = (t + 1) < NT;
    const int k1 = (t + 1) << 6;
    bf16x8 av[4], bv[4];

    // ---- phase 1: kk0, M-half0 ----
#pragma unroll
    for (int i = 0; i < 4; i++) av[i] = RD_A4(p, 0, wm + i * 16 + fr);
#pragma unroll
    for (int n = 0; n < 4; n++) bv[n] = RD_B4(p, 0, wn + n * 16 + fr);
    if (st) { STG_B4(p ^ 1, k1, 0); STG_B4(p ^ 1, k1, 1); vmcnt2(); } else vmcnt0();
    __builtin_amdgcn_s_barrier();   // BARRIER1: A1,A3 landed across waves
    __builtin_amdgcn_s_setprio(1);
#pragma unroll
    for (int i = 0; i < 4; i++)
#pragma unroll
      for (int n = 0; n < 4; n++)
        acc[i][n] = __builtin_amdgcn_mfma_f32_16x16x32_bf16(av[i], bv[n], acc[i][n], 0, 0, 0);
    __builtin_amdgcn_s_setprio(0);

    // ---- phase 2: kk0, M-half1 (reuse bv) ----
#pragma unroll
    for (int i = 0; i < 4; i++) av[i] = RD_A4(p, 0, wm + 64 + i * 16 + fr);
    if (st) { STG_B4(p ^ 1, k1, 2); STG_B4(p ^ 1, k1, 3); vmcnt2(); }
    __builtin_amdgcn_s_setprio(1);
#pragma unroll
    for (int i = 0; i < 4; i++)
#pragma unroll
      for (int n = 0; n < 4; n++)
        acc[4 + i][n] = __builtin_amdgcn_mfma_f32_16x16x32_bf16(av[i], bv[n], acc[4 + i][n], 0, 0, 0);
    __builtin_amdgcn_s_setprio(0);

    // ---- phase 3: kk1, M-half0 ----
#pragma unroll
    for (int i = 0; i < 4; i++) av[i] = RD_A4(p, 1, wm + i * 16 + fr);
#pragma unroll
    for (int n = 0; n < 4; n++) bv[n] = RD_B4(p, 1, wn + n * 16 + fr);
    if (st) { STG_A4(p ^ 1, k1, 0); STG_A4(p ^ 1, k1, 2); vmcnt2(); }
    __builtin_amdgcn_s_setprio(1);
#pragma unroll
    for (int i = 0; i < 4; i++)
#pragma unroll
      for (int n = 0; n < 4; n++)
        acc[i][n] = __builtin_amdgcn_mfma_f32_16x16x32_bf16(av[i], bv[n], acc[i][n], 0, 0, 0);
    __builtin_amdgcn_s_setprio(0);

    // ---- phase 4: kk1, M-half1 (reuse bv) ----
#pragma unroll
    for (int i = 0; i < 4; i++) av[i] = RD_A4(p, 1, wm + 64 + i * 16 + fr);
    if (st) { STG_A4(p ^ 1, k1, 1); STG_A4(p ^ 1, k1, 3); vmcnt2(); }
    __builtin_amdgcn_s_setprio(1);
#pragma unroll
    for (int i = 0; i < 4; i++)
#pragma unroll
      for (int n = 0; n < 4; n++)
        acc[4 + i][n] = __builtin_amdgcn_mfma_f32_16x16x32_bf16(av[i], bv[n], acc[4 + i][n], 0, 0, 0);
    __builtin_amdgcn_s_setprio(0);
    __builtin_amdgcn_s_barrier();   // TRAILING: WAR + cross-wave landing of t+1 data
  }
#undef STG_A4
#undef STG_B4
#undef RD_A4
#undef RD_B4

#pragma unroll
  for (int m = 0; m < 8; m++)
#pragma unroll
    for (int n = 0; n < 4; n++)
#pragma unroll
      for (int j = 0; j < 4; j++) {
        int row = m0 + wm + m * 16 + fq * 4 + j;
        int col = n0 + wn + n * 16 + fr;
        size_t idx = (size_t)row * N + col;
        float v = acc[m][n][j];
        if (EPI == 0) ((u16*)Cv)[idx] = f2bf(v);
        else if (EPI == 1) ((float*)Cv)[idx] = v + res[idx];
        else if (EPI == 2) { float r = v > 0.f ? v : 0.f; ((u16*)Cv)[idx] = f2bf(r * r); }
        else ((u16*)Cv)[idx] = f2bf(1.f / (1.f + expf(-v)));
      }
}

// ---- gemm3b: BM=128, BN=256, 3-buffer ring (depth-2), 2 phases x 16 MFMA,
// one barrier + one counted vmcnt(6) per tile. gx>0: by-major mapping
// (by = wg/gx -> per-XCD single B panel that fits L2).
// EPI: 9 = f32 out = out + bf16(sr)*acc
template <int EPI>
__global__ __launch_bounds__(512) void gemm3b(const u16* __restrict__ A,
                                              const u16* __restrict__ Bt,
                                              void* __restrict__ Cv,
                                              const u16* __restrict__ srp,
                                              int N, int K, int lda, int ldb,
                                              int gy, int gx) {
  __shared__ alignas(16) char smem[3 * 49152];
  const int nwg = gridDim.x, qq = nwg >> 3;
  const int wg = (int)(blockIdx.x & 7) * qq + (int)(blockIdx.x >> 3);
  int bx, by;
  if (gx > 0) { by = wg / gx; bx = wg - by * gx; }
  else { bx = wg / gy; by = wg - bx * gy; }
  const int tid = threadIdx.x, w = tid >> 6, lane = tid & 63;
  const int fr = lane & 15, fq = lane >> 4;
  const int m0 = bx * 128, n0 = by * 256;
  const int wm = (w >> 2) * 64, wn = (w & 3) * 64;
  const int rowS = tid >> 3;
  const int colS = ((tid & 7) * 8) ^ ((rowS & 7) << 3);
  const u16* Ag = A + (size_t)(m0 + rowS) * lda + colS;
  const u16* Bg = Bt + (size_t)(n0 + rowS) * ldb + colS;
  const int NT = K >> 6;

  f32x4 acc[4][4];
#pragma unroll
  for (int m = 0; m < 4; m++)
#pragma unroll
    for (int n = 0; n < 4; n++) acc[m][n] = (f32x4){0.f, 0.f, 0.f, 0.f};

#define STG_A(buf, k0, j) GLOAD16(Ag + (size_t)((j) * 64) * lda + (k0), \
    smem + (buf) * 49152 + (j) * 8192 + w * 1024)
#define STG_B(buf, k0, j) GLOAD16(Bg + (size_t)((j) * 64) * ldb + (k0), \
    smem + (buf) * 49152 + 16384 + (j) * 8192 + w * 1024)
#define RD_A(buf, kk, m) (*(const bf16x8*)(smem + (buf) * 49152 + \
    ((((wm + (m) * 16 + fr) * 128) + (kk) * 64 + fq * 16) ^ (((wm + (m) * 16 + fr) & 7) << 4))))
#define RD_B(buf, kk, n) (*(const bf16x8*)(smem + (buf) * 49152 + 16384 + \
    ((((wn + (n) * 16 + fr) * 128) + (kk) * 64 + fq * 16) ^ (((wn + (n) * 16 + fr) & 7) << 4))))

  STG_A(0, 0, 0); STG_A(0, 0, 1);
  STG_B(0, 0, 0); STG_B(0, 0, 1); STG_B(0, 0, 2); STG_B(0, 0, 3);
  STG_A(1, 64, 0); STG_A(1, 64, 1);
  STG_B(1, 64, 0); STG_B(1, 64, 1); STG_B(1, 64, 2); STG_B(1, 64, 3);
  vmcnt6();
  __builtin_amdgcn_s_barrier();

  int bufc = 0;
  for (int t = 0; t < NT; t++) {
    int b2 = bufc + 2; if (b2 >= 3) b2 -= 3;
    const bool st = (t + 2) < NT;
    const int k2 = (t + 2) << 6;
    bf16x8 av[4], bv[4];

#pragma unroll
    for (int m = 0; m < 4; m++) av[m] = RD_A(bufc, 0, m);
#pragma unroll
    for (int n = 0; n < 4; n++) bv[n] = RD_B(bufc, 0, n);
    if (st) { STG_A(b2, k2, 0); STG_A(b2, k2, 1); STG_B(b2, k2, 0); }
    __builtin_amdgcn_s_setprio(1);
#pragma unroll
    for (int m = 0; m < 4; m++)
#pragma unroll
      for (int n = 0; n < 4; n++)
        acc[m][n] = __builtin_amdgcn_mfma_f32_16x16x32_bf16(av[m], bv[n], acc[m][n], 0, 0, 0);
    __builtin_amdgcn_s_setprio(0);

#pragma unroll
    for (int m = 0; m < 4; m++) av[m] = RD_A(bufc, 1, m);
#pragma unroll
    for (int n = 0; n < 4; n++) bv[n] = RD_B(bufc, 1, n);
    if (st) { STG_B(b2, k2, 1); STG_B(b2, k2, 2); STG_B(b2, k2, 3); }
    if (st) vmcnt6(); else vmcnt0();
    __builtin_amdgcn_s_setprio(1);
#pragma unroll
    for (int m = 0; m < 4; m++)
#pragma unroll
      for (int n = 0; n < 4; n++)
        acc[m][n] = __builtin_amdgcn_mfma_f32_16x16x32_bf16(av[m], bv[n], acc[m][n], 0, 0, 0);
    __builtin_amdgcn_s_setprio(0);
    __builtin_amdgcn_s_barrier();

    bufc = bufc + 1 == 3 ? 0 : bufc + 1;
  }
#undef STG_A
#undef STG_B
#undef RD_A
#undef RD_B

#pragma unroll
  for (int m = 0; m < 4; m++)
#pragma unroll
    for (int n = 0; n < 4; n++)
#pragma unroll
      for (int j = 0; j < 4; j++) {
        int row = m0 + wm + m * 16 + fq * 4 + j;
        int col = n0 + wn + n * 16 + fr;
        size_t idx = (size_t)row * N + col;
        float v = acc[m][n][j];
        if (EPI == 9) {
          float pvv = ((float*)Cv)[idx];
          ((float*)Cv)[idx] = pvv + bf2f(srp[idx]) * v;
        } else {
          ((u16*)Cv)[idx] = f2bf(v);
        }
      }
}

// ---- kvsum: per-chunk S_c[s][sv] = sum_t wk[t]*K[t][s]*V[t][sv]  (MFMA) -----
__global__ __launch_bounds__(256) void kvsum_m(const u16* __restrict__ K,
                                               const u16* __restrict__ V,
                                               const float* __restrict__ wk_tab,
                                               float* __restrict__ SC) {
  const int bh = blockIdx.x & 127, c = blockIdx.x >> 7;
  const int b = bh >> 5, h = bh & 31;
  const int tid = threadIdx.x, w = tid >> 6, lane = tid & 63;
  const int fr = lane & 15, fq = lane >> 4;
  const size_t chunkbase = (size_t)b * TT_ + (size_t)c * TCH;
  const u16* Kp = K + chunkbase * C_ + h * 64;
  const u16* Vp = V + chunkbase * C_ + h * 64;
  __shared__ alignas(16) u16 Kts[64 * 128];
  __shared__ alignas(16) u16 Vts[64 * 128];
  f32x4 acc[4];
#pragma unroll
  for (int n = 0; n < 4; n++) acc[n] = (f32x4){0.f, 0.f, 0.f, 0.f};

  for (int tb = 0; tb < 4; tb++) {
    __syncthreads();
    const int u = tid >> 1;
    const int tg = tb * 128 + u;
    const float wkv = wk_tab[h * TCH + tg];
#pragma unroll
    for (int i = 0; i < 4; i++) {
      int s0 = (tid & 1) * 32 + i * 8;
      uint4 dK = *(const uint4*)(Kp + (size_t)tg * C_ + s0);
      uint4 dV = *(const uint4*)(Vp + (size_t)tg * C_ + s0);
      const u16* ek = (const u16*)&dK;
      const u16* ev = (const u16*)&dV;
#pragma unroll
      for (int j = 0; j < 8; j++) {
        int s = s0 + j;
        int byte = s * 256 + u * 2;
        byte ^= (s & 7) << 4;
        *(u16*)((char*)Kts + byte) = f2bf(bf2f(ek[j]) * wkv);
        *(u16*)((char*)Vts + byte) = ev[j];
      }
    }
    __syncthreads();
#pragma unroll
    for (int kk = 0; kk < 4; kk++) {
      int rbyteA = (w * 16 + fr) * 256 + kk * 64 + fq * 16;
      rbyteA ^= (fr & 7) << 4;
      bf16x8 av = *(const bf16x8*)((char*)Kts + rbyteA);
#pragma unroll
      for (int n = 0; n < 4; n++) {
        int rbyteB = (n * 16 + fr) * 256 + kk * 64 + fq * 16;
        rbyteB ^= (fr & 7) << 4;
        bf16x8 bv = *(const bf16x8*)((char*)Vts + rbyteB);
        acc[n] = __builtin_amdgcn_mfma_f32_16x16x32_bf16(av, bv, acc[n], 0, 0, 0);
      }
    }
  }
  float* out = SC + ((size_t)c * 128 + bh) * 4096;
#pragma unroll
  for (int n = 0; n < 4; n++)
#pragma unroll
    for (int j = 0; j < 4; j++) {
      int srow = w * 16 + fq * 4 + j;
      int scol = n * 16 + fr;
      out[srow * 64 + scol] = acc[n][j];
    }
}

// ---- state combine: STt[c][s][sp] = bf16( sum_{j<c} ws^(c-1-j) SC[j][sp][s] )
__global__ __launch_bounds__(256) void stcomb(const float* __restrict__ SC,
                                              u16* __restrict__ STt,
                                              const float* __restrict__ wspow) {
  const int bh = blockIdx.x;
  const float ws = wspow[bh & 31];
  const int tid = threadIdx.x;
#pragma unroll
  for (int e = 0; e < 16; e++) {
    int idxT = e * 256 + tid;
    int s = idxT >> 6, sp = idxT & 63;
    int src = sp * 64 + s;
    float st = 0.f;
#pragma unroll
    for (int c = 0; c < 4; c++) {
      STt[((size_t)c * 128 + bh) * 4096 + idxT] = f2bf(st);
      st = ws * st + SC[((size_t)c * 128 + bh) * 4096 + src];
    }
  }
}

// ---- attention output (MFMA, batched over chunks) + FUSED GROUPNORM ---------
__global__ __launch_bounds__(256) void att_out_m(const u16* __restrict__ R,
                                                 const u16* __restrict__ K,
                                                 const u16* __restrict__ V,
                                                 const u16* __restrict__ STt,
                                                 const float* __restrict__ wb_tab,
                                                 const float* __restrict__ u_vec,
                                                 const float* __restrict__ lnxg,
                                                 const float* __restrict__ lnxb,
                                                 u16* __restrict__ xan) {
  const int bh = blockIdx.x;
  const int ti = blockIdx.y;
  const int c  = blockIdx.z;
  const int b = bh >> 5, h = bh & 31;
  const int tid = threadIdx.x, w = tid >> 6, lane = tid & 63;
  const int fr = lane & 15, fq = lane >> 4;
  const int t0 = ti * 64;
  const size_t chunkbase = (size_t)b * TT_ + (size_t)c * TCH;
  const u16* Rp = R + (chunkbase + t0) * C_ + h * 64;
  const u16* Kp = K + chunkbase * C_ + h * 64;
  const u16* Vp = V + chunkbase * C_ + h * 64;

  __shared__ alignas(16) u16 Rs[64 * 64];
  __shared__ alignas(16) u16 Ks[64 * 64];
  __shared__ alignas(16) u16 Vts[64 * 64];
  __shared__ alignas(16) u16 Xs[64 * 64];
  __shared__ float wbs[512];

#pragma unroll
  for (int it = 0; it < 2; it++) {
    int r = (tid >> 3) + it * 32;
    int cb = (tid & 7) * 16;
    uint4 d = *(const uint4*)((const char*)(Rp + (size_t)r * C_) + cb);
    int byte = (r * 128 + cb) ^ ((r & 7) << 4);
    *(uint4*)((char*)Rs + byte) = d;
  }
  const u16* stg = STt + ((size_t)c * 128 + bh) * 4096;
#pragma unroll
  for (int it = 0; it < 2; it++) {
    int s = (tid >> 3) + it * 32;
    int cb = (tid & 7) * 16;
    uint4 d = *(const uint4*)((const char*)(stg + (size_t)s * 64) + cb);
    int byte = (s * 128 + cb) ^ ((s & 7) << 4);
    *(uint4*)((char*)Xs + byte) = d;
  }
  wbs[tid] = wb_tab[h * TCH + tid];
  wbs[tid + 256] = wb_tab[h * TCH + tid + 256];
  const float uh = u_vec[h];
  __syncthreads();

  f32x4 pv[4];
#pragma unroll
  for (int n = 0; n < 4; n++) pv[n] = (f32x4){0.f, 0.f, 0.f, 0.f};
#pragma unroll
  for (int kk = 0; kk < 2; kk++) {
    int rbA = ((w * 16 + fr) * 128 + kk * 64 + fq * 16) ^ ((fr & 7) << 4);
    bf16x8 av = *(const bf16x8*)((char*)Rs + rbA);
#pragma unroll
    for (int n = 0; n < 4; n++) {
      int rbB = ((n * 16 + fr) * 128 + kk * 64 + fq * 16) ^ ((fr & 7) << 4);
      bf16x8 bv = *(const bf16x8*)((char*)Xs + rbB);
      pv[n] = __builtin_amdgcn_mfma_f32_16x16x32_bf16(av, bv, pv[n], 0, 0, 0);
    }
  }
#pragma unroll
  for (int n = 0; n < 4; n++)
#pragma unroll
    for (int j = 0; j < 4; j++) {
      int tg = t0 + w * 16 + fq * 4 + j;
      pv[n][j] *= wbs[tg];
    }

  for (int ub = 0; ub <= ti; ub++) {
    const int u0 = ub * 64;
    __syncthreads();
#pragma unroll
    for (int it = 0; it < 2; it++) {
      int r = (tid >> 3) + it * 32;
      int cb = (tid & 7) * 16;
      uint4 d = *(const uint4*)((const char*)(Kp + (size_t)(u0 + r) * C_) + cb);
      int byte = (r * 128 + cb) ^ ((r & 7) << 4);
      *(uint4*)((char*)Ks + byte) = d;
    }
#pragma unroll
    for (int it = 0; it < 2; it++) {
      int u = (tid >> 3) + it * 32;
      int s0 = (tid & 7) * 8;
      uint4 d = *(const uint4*)(Vp + (size_t)(u0 + u) * C_ + s0);
      const u16* ev = (const u16*)&d;
#pragma unroll
      for (int j = 0; j < 8; j++) {
        int s = s0 + j;
        int byte = (s * 128 + u * 2) ^ ((s & 7) << 4);
        *(u16*)((char*)Vts + byte) = ev[j];
      }
    }
    __syncthreads();
    f32x4 accA[4];
#pragma unroll
    for (int n = 0; n < 4; n++) accA[n] = (f32x4){0.f, 0.f, 0.f, 0.f};
#pragma unroll
    for (int kk = 0; kk < 2; kk++) {
      int rbA = ((w * 16 + fr) * 128 + kk * 64 + fq * 16) ^ ((fr & 7) << 4);
      bf16x8 av = *(const bf16x8*)((char*)Rs + rbA);
#pragma unroll
      for (int n = 0; n < 4; n++) {
        int rbB = ((n * 16 + fr) * 128 + kk * 64 + fq * 16) ^ ((fr & 7) << 4);
        bf16x8 bv = *(const bf16x8*)((char*)Ks + rbB);
        accA[n] = __builtin_amdgcn_mfma_f32_16x16x32_bf16(av, bv, accA[n], 0, 0, 0);
      }
    }
#pragma unroll
    for (int n = 0; n < 4; n++) {
#pragma unroll
      for (int j = 0; j < 4; j++) {
        int tl = w * 16 + fq * 4 + j;
        int tg = t0 + tl;
        int u = u0 + n * 16 + fr;
        int d = tg - u;
        float f = (d > 0) ? wbs[d - 1] : ((d == 0) ? uh : 0.f);
        int byte = (tl * 128 + (n * 16 + fr) * 2) ^ ((tl & 7) << 4);
        *(u16*)((char*)Xs + byte) = f2bf(accA[n][j] * f);
      }
    }
#pragma unroll
    for (int kk = 0; kk < 2; kk++) {
      int rbA = ((w * 16 + fr) * 128 + kk * 64 + fq * 16) ^ ((fr & 7) << 4);
      bf16x8 ap = *(const bf16x8*)((char*)Xs + rbA);
#pragma unroll
      for (int n = 0; n < 4; n++) {
        int rbB = ((n * 16 + fr) * 128 + kk * 64 + fq * 16) ^ ((fr & 7) << 4);
        bf16x8 vp = *(const bf16x8*)((char*)Vts + rbB);
        pv[n] = __builtin_amdgcn_mfma_f32_16x16x32_bf16(ap, vp, pv[n], 0, 0, 0);
      }
    }
  }

  // ---- fused groupnorm epilogue ----
#pragma unroll
  for (int n = 0; n < 4; n++)
#pragma unroll
    for (int j = 0; j < 4; j++) pv[n][j] *= 0.125f;
  float rm[4], ri[4];
#pragma unroll
  for (int j = 0; j < 4; j++) {
    float s = pv[0][j] + pv[1][j] + pv[2][j] + pv[3][j];
    float s2 = pv[0][j] * pv[0][j] + pv[1][j] * pv[1][j] +
               pv[2][j] * pv[2][j] + pv[3][j] * pv[3][j];
#pragma unroll
    for (int o = 1; o < 16; o <<= 1) { s += __shfl_xor(s, o); s2 += __shfl_xor(s2, o); }
    float m = s * (1.f / 64.f);
    float var = s2 * (1.f / 64.f) - m * m;
    rm[j] = m;
    ri[j] = rsqrtf(var + 1e-5f);
  }
  const float* gg = lnxg + h * 64;
  const float* bb = lnxb + h * 64;
  u16* xout = xan + (chunkbase + t0) * C_ + h * 64;
#pragma unroll
  for (int n = 0; n < 4; n++)
#pragma unroll
    for (int j = 0; j < 4; j++) {
      int tl = w * 16 + fq * 4 + j;
      int col = n * 16 + fr;
      float nv = (pv[n][j] - rm[j]) * ri[j];
      xout[(size_t)tl * C_ + col] = f2bf(nv * gg[col] + bb[col]);
    }
}

// ---- launcher ---------------------------------------------------------------
extern "C" void kernel_launch(void* const* d_in, const int* in_sizes, int n_in,
                              void* d_out, int out_size, void* d_ws, size_t ws_size,
                              hipStream_t stream) {
  (void)in_sizes; (void)n_in; (void)out_size; (void)ws_size;
  const float* x    = (const float*)d_in[0];
  const float* ln1g = (const float*)d_in[1];
  const float* ln1b = (const float*)d_in[2];
  const float* ln2g = (const float*)d_in[3];
  const float* ln2b = (const float*)d_in[4];
  const float* amk  = (const float*)d_in[5];
  const float* amv  = (const float*)d_in[6];
  const float* amr  = (const float*)d_in[7];
  const float* tdec = (const float*)d_in[8];
  const float* tfaa = (const float*)d_in[9];
  const float* Wr   = (const float*)d_in[10];
  const float* Wk   = (const float*)d_in[11];
  const float* Wv   = (const float*)d_in[12];
  const float* Wo   = (const float*)d_in[13];
  const float* lnxg = (const float*)d_in[14];
  const float* lnxb = (const float*)d_in[15];
  const float* fmk  = (const float*)d_in[16];
  const float* fmr  = (const float*)d_in[17];
  const float* Wfk  = (const float*)d_in[18];
  const float* Wfr  = (const float*)d_in[19];
  const float* Wfv  = (const float*)d_in[20];

  char* ws = (char*)d_ws;
  const size_t MB = 1ull << 20;
  u16* WR  = (u16*)(ws + 0 * MB);
  u16* WK  = (u16*)(ws + 8 * MB);
  u16* WV  = (u16*)(ws + 16 * MB);
  u16* WO  = (u16*)(ws + 24 * MB);
  u16* WFR = (u16*)(ws + 32 * MB);
  u16* WFK = (u16*)(ws + 40 * MB);
  u16* WFV = (u16*)(ws + 68 * MB);
  u16* H1  = (u16*)(ws + 96 * MB);
  u16* XR  = (u16*)(ws + 128 * MB);
  u16* XK  = (u16*)(ws + 160 * MB);
  u16* XV  = (u16*)(ws + 192 * MB);
  float* WBT = (float*)(ws + 224 * MB);
  float* WKT = (float*)(ws + 224 * MB + 65536);
  float* WSP = (float*)(ws + 224 * MB + 131072);
  float* SCb = (float*)(ws + 0 * MB);
  u16* STTb  = (u16*)(ws + 8 * MB);
  u16* RB   = H1;
  u16* KB   = XR;
  u16* VB   = XK;
  u16* XAN  = H1;                    // fused gnorm writes in place over R
  u16* XK2  = WR;
  u16* XR2  = H1;
  u16* SR   = XR;
  u16* KFH  = XK;                    // (4096, 7168) bf16 M-half = 56 MB (160-216)
  float* OUT = (float*)d_out;

  dim3 blk(256), gblk(512);
  wcvt_t<<<dim3(32, 32), blk, 0, stream>>>(Wr, WR, 2048, 2048, 0);
  wcvt_t<<<dim3(32, 32), blk, 0, stream>>>(Wk, WK, 2048, 2048, 0);
  wcvt_t<<<dim3(32, 32), blk, 0, stream>>>(Wv, WV, 2048, 2048, 0);
  wcvt_t<<<dim3(32, 32), blk, 0, stream>>>(Wo, WO, 2048, 2048, 0);
  wcvt_t<<<dim3(32, 32), blk, 0, stream>>>(Wfr, WFR, 2048, 2048, 0);
  wcvt_t<<<dim3(112, 32), blk, 0, stream>>>(Wfk, WFK, 2048, 7168, 0);
  wcvt_t<<<dim3(32, 112), blk, 0, stream>>>(Wfv, WFV, 7168, 2048, 0);

  // ---- attention branch ----
  ln_mix3<<<8192, blk, 0, stream>>>(x, ln1g, ln1b, amk, amv, amr, XK, XV, XR);
  gemm4<0><<<256, gblk, 0, stream>>>(XR, WR, RB, nullptr, 2048, 2048, 2048, 2048, 8, 1);
  gemm4<0><<<256, gblk, 0, stream>>>(XK, WK, KB, nullptr, 2048, 2048, 2048, 2048, 8, 1);
  gemm4<0><<<256, gblk, 0, stream>>>(XV, WV, VB, nullptr, 2048, 2048, 2048, 2048, 8, 1);

  wtabs_k<<<32, 512, 0, stream>>>(tdec, WBT, WKT, WSP);
  kvsum_m<<<512, blk, 0, stream>>>(KB, VB, WKT, SCb);
  stcomb<<<128, blk, 0, stream>>>(SCb, STTb, WSP);
  att_out_m<<<dim3(128, 8, 4), blk, 0, stream>>>(RB, KB, VB, STTb, WBT, tfaa,
                                                 lnxg, lnxb, XAN);

  gemm4<1><<<256, gblk, 0, stream>>>(XAN, WO, OUT, x, 2048, 2048, 2048, 2048, 8, 1);

  // ---- FFN branch (M-split) ----
  ln_mix2<<<8192, blk, 0, stream>>>(OUT, ln2g, ln2b, fmk, fmr, XK2, XR2);
  gemm4<3><<<256, gblk, 0, stream>>>(XR2, WFR, SR, nullptr, 2048, 2048, 2048, 2048, 8, 1);

  for (int half = 0; half < 2; half++) {
    const u16* a_half = XK2 + (size_t)half * 4096 * 2048;
    gemm4<2><<<448, gblk, 0, stream>>>(a_half, WFK, KFH, nullptr,
                                       7168, 2048, 2048, 2048, 28, 8);
    // by-major: each XCD owns one by (256x7168x2B = 3.6 MB B panel fits L2)
    gemm3b<9><<<256, gblk, 0, stream>>>(KFH, WFV, OUT + (size_t)half * 4096 * 2048,
                                        SR + (size_t)half * 4096 * 2048,
                                        2048, 7168, 7168, 7168, 8, 32);
  }
}